// Round 2
// baseline (20165.945 us; speedup 1.0000x reference)
//
#include <hip/hip_runtime.h>
#include <math.h>

// ---------------- problem constants ----------------
#define B_   8
#define L_   24
#define LP_  48
#define N_   325
#define D_   128
#define H_   8
#define NL_  3
#define DFF_ 512

static const int  ROWS   = B_ * L_ * N_;         // 62400 tokens of x
static const int  T_SELF = L_ * N_;              // 7800
static const int  T_CROSS= LP_ * N_;             // 15600
static const long long SZ = (long long)B_ * L_ * N_ * D_;   // 7,987,200 floats
static const long long U_  = (long long)T_SELF * D_;        // 998,400 per-b x floats
static const long long C2_ = (long long)T_CROSS * D_;       // 1,996,800 per-b mem floats

enum { EPI_NONE = 0, EPI_ELU1 = 1, EPI_GELU = 2 };

// ---------------- generic tiled GEMM ----------------
// C[batch][M,Nc] (= or +=) epi( A[batch][M,K] @ Bm[batch%bmod][K,Nc] + bias[batch%bmod][Nc] )
// transA: A stored [K,M] row-major (A[k*lda+m]).
#define TS  64
#define KSZ 16

__global__ __launch_bounds__(256) void gemm_k(
    const float* __restrict__ A, const float* __restrict__ Bm,
    const float* __restrict__ bias, float* __restrict__ C,
    int M, int Nc, int K,
    long long sA, long long sB, long long sC,
    int lda, int ldb, int ldc,
    int bmod, long long sBias,
    int transA, int accum, int epi)
{
    const int batch = blockIdx.z;
    A  += (long long)batch * sA;
    Bm += (long long)(batch % bmod) * sB;
    C  += (long long)batch * sC;
    const float* bp = bias ? (bias + (long long)(batch % bmod) * sBias) : nullptr;

    const int m0 = blockIdx.y * TS;
    const int n0 = blockIdx.x * TS;
    const int tid = threadIdx.x;
    const int tx = tid & 15, ty = tid >> 4;

    __shared__ float As[KSZ][TS + 1];
    __shared__ float Bs[KSZ][TS + 1];

    float acc[4][4];
#pragma unroll
    for (int i = 0; i < 4; ++i)
#pragma unroll
        for (int j = 0; j < 4; ++j) acc[i][j] = 0.f;

    for (int k0 = 0; k0 < K; k0 += KSZ) {
        if (!transA) {
#pragma unroll
            for (int r = 0; r < 4; ++r) {
                int idx = tid + r * 256;          // over [64 m][16 k]
                int i = idx >> 4, j = idx & 15;
                int m = m0 + i, k = k0 + j;
                As[j][i] = (m < M && k < K) ? A[(long long)m * lda + k] : 0.f;
            }
        } else {
#pragma unroll
            for (int r = 0; r < 4; ++r) {
                int idx = tid + r * 256;          // over [16 k][64 m]
                int j = idx >> 6, i2 = idx & 63;
                int m = m0 + i2, k = k0 + j;
                As[j][i2] = (m < M && k < K) ? A[(long long)k * lda + m] : 0.f;
            }
        }
#pragma unroll
        for (int r = 0; r < 4; ++r) {
            int idx = tid + r * 256;              // over [16 k][64 n]
            int j = idx >> 6, n = idx & 63;
            int k = k0 + j, nn = n0 + n;
            Bs[j][n] = (k < K && nn < Nc) ? Bm[(long long)k * ldb + nn] : 0.f;
        }
        __syncthreads();
#pragma unroll
        for (int kk = 0; kk < KSZ; ++kk) {
            float a[4], b[4];
#pragma unroll
            for (int i = 0; i < 4; ++i) a[i] = As[kk][ty * 4 + i];
#pragma unroll
            for (int j = 0; j < 4; ++j) b[j] = Bs[kk][tx * 4 + j];
#pragma unroll
            for (int i = 0; i < 4; ++i)
#pragma unroll
                for (int j = 0; j < 4; ++j)
                    acc[i][j] = fmaf(a[i], b[j], acc[i][j]);
        }
        __syncthreads();
    }

#pragma unroll
    for (int i = 0; i < 4; ++i) {
        int m = m0 + ty * 4 + i;
        if (m >= M) continue;
#pragma unroll
        for (int j = 0; j < 4; ++j) {
            int n = n0 + tx * 4 + j;
            if (n >= Nc) continue;
            float v = acc[i][j];
            if (bp) v += bp[n];
            if (epi == EPI_ELU1)      v = (v > 0.f) ? (v + 1.f) : expf(v);
            else if (epi == EPI_GELU) v = 0.5f * v * (1.f + erff(v * 0.70710678118654752f));
            long long ci = (long long)m * ldc + n;
            if (accum) C[ci] += v; else C[ci] = v;
        }
    }
}

static inline void launch_gemm(hipStream_t st, const float* A, const float* Bm,
                               const float* bias, float* C,
                               int M, int Nc, int K,
                               long long sA, long long sB, long long sC,
                               int lda, int ldb, int ldc,
                               int batches, int bmod, long long sBias,
                               int transA, int accum, int epi)
{
    dim3 grid((Nc + TS - 1) / TS, (M + TS - 1) / TS, batches);
    gemm_k<<<grid, 256, 0, st>>>(A, Bm, bias, C, M, Nc, K, sA, sB, sC,
                                 lda, ldb, ldc, bmod, sBias, transA, accum, epi);
}

// ---------------- linear attention: partial kv over T-chunks ----------------
// part[(tc,h)][e*16+d] = sum_{t in chunk} kp[t, h*16+e] * v[t, h*16+d]
// part[(tc,h)][256+e]  = sum_{t in chunk} kp[t, h*16+e]
__global__ __launch_bounds__(256) void kv_part_kernel(
    const float* __restrict__ kp, const float* __restrict__ v,
    float* __restrict__ part, int T, int tchunk)
{
    const int h = blockIdx.y;
    const int t0 = blockIdx.x * tchunk;
    const int tend = min(T, t0 + tchunk);
    const int tid = threadIdx.x;
    const int e = tid >> 4, d = tid & 15;
    __shared__ float sk[64][16];
    __shared__ float sv[64][16];
    float acc = 0.f, asum = 0.f;
    for (int tb = t0; tb < tend; tb += 64) {
#pragma unroll
        for (int r = 0; r < 4; ++r) {
            int idx = tid + r * 256;
            int tt = idx >> 4, c = idx & 15;
            int t = tb + tt;
            if (t < tend) {
                long long gi = (long long)t * D_ + h * 16 + c;
                sk[tt][c] = kp[gi];
                sv[tt][c] = v[gi];
            } else { sk[tt][c] = 0.f; sv[tt][c] = 0.f; }
        }
        __syncthreads();
#pragma unroll 8
        for (int tt = 0; tt < 64; ++tt) {
            float ke = sk[tt][e];
            acc  = fmaf(ke, sv[tt][d], acc);
            asum += ke;
        }
        __syncthreads();
    }
    float* pp = part + ((long long)blockIdx.x * H_ + h) * 272;
    pp[e * 16 + d] = acc;
    if (d == 0) pp[256 + e] = asum;
}

// deterministic tree-free serial reduce over chunks (TC <= 31)
__global__ __launch_bounds__(256) void kv_reduce_kernel(
    const float* __restrict__ part, float* __restrict__ kv,
    float* __restrict__ ksum, int b, int TC)
{
    const int h = blockIdx.x;
    const int tid = threadIdx.x;
    const int e = tid >> 4, d = tid & 15;
    float acc = 0.f;
    for (int tc = 0; tc < TC; ++tc)
        acc += part[((long long)tc * H_ + h) * 272 + e * 16 + d];
    kv[((long long)(b * H_ + h) * 16 + e) * 16 + d] = acc;
    if (d == 0) {
        float s = 0.f;
        for (int tc = 0; tc < TC; ++tc)
            s += part[((long long)tc * H_ + h) * 272 + 256 + e];
        ksum[(b * H_ + h) * 16 + e] = s;
    }
}

// ---------------- attention combine (safe in-place: out may == qp) ----------
__global__ __launch_bounds__(256) void attn_out_kernel(
    const float* __restrict__ qp, const float* __restrict__ kv,
    const float* __restrict__ ksum, float* __restrict__ out, int SperB)
{
    const int row = blockIdx.x * 2 + threadIdx.y;
    const int o = threadIdx.x;
    const int h = o >> 4, dp = o & 15;
    __shared__ float sq[2][D_];
    const int b = row / SperB;
    sq[threadIdx.y][o] = qp[(long long)row * D_ + o];
    __syncthreads();
    const float* ks  = ksum + (b * H_ + h) * 16;
    const float* kvp = kv + (long long)(b * H_ + h) * 256 + dp;
    float den = 1e-6f, acc = 0.f;
#pragma unroll
    for (int e = 0; e < 16; ++e) {
        float q = sq[threadIdx.y][h * 16 + e];
        den = fmaf(q, ks[e], den);
        acc = fmaf(q, kvp[e * 16], acc);
    }
    out[(long long)row * D_ + o] = acc / den;
}

// ---------------- fused (residual|relu) + LayerNorm (row-local, in-place ok)
__global__ __launch_bounds__(256) void addln_kernel(
    const float* __restrict__ xin, const float* __restrict__ addend,
    const float* __restrict__ g, const float* __restrict__ beta,
    float* __restrict__ outp, int relu_mode)
{
    const int row = blockIdx.x * 4 + threadIdx.y;
    const int lane = threadIdx.x;                       // one wave per row
    const long long base = (long long)row * D_;
    float v0 = xin[base + lane], v1 = xin[base + lane + 64];
    if (addend) { v0 += addend[base + lane]; v1 += addend[base + lane + 64]; }
    if (relu_mode) { v0 = fmaxf(v0, 0.f); v1 = fmaxf(v1, 0.f); }
    float s = v0 + v1;
#pragma unroll
    for (int off = 32; off; off >>= 1) s += __shfl_xor(s, off);
    const float mean = s * (1.f / 128.f);
    const float c0 = v0 - mean, c1 = v1 - mean;
    float vs = c0 * c0 + c1 * c1;
#pragma unroll
    for (int off = 32; off; off >>= 1) vs += __shfl_xor(vs, off);
    const float rstd = rsqrtf(vs * (1.f / 128.f) + 1e-5f);
    outp[base + lane]      = c0 * rstd * g[lane] + beta[lane];
    outp[base + lane + 64] = c1 * rstd * g[lane + 64] + beta[lane + 64];
}

// ---------------- driver ----------------
extern "C" void kernel_launch(void* const* d_in, const int* in_sizes, int n_in,
                              void* d_out, int out_size, void* d_ws, size_t ws_size,
                              hipStream_t stream)
{
    (void)in_sizes; (void)n_in; (void)out_size; (void)ws_size;

    const float* x_in    = (const float*)d_in[0];
    const float* mem     = (const float*)d_in[1];
    const float* data    = (const float*)d_in[2];
    const float* support = (const float*)d_in[3];
    const float* Wq  = (const float*)d_in[4];
    const float* bq  = (const float*)d_in[5];
    const float* Wk  = (const float*)d_in[6];
    const float* bk  = (const float*)d_in[7];
    const float* Wv  = (const float*)d_in[8];
    const float* bv  = (const float*)d_in[9];
    const float* Wo  = (const float*)d_in[10];
    const float* bo  = (const float*)d_in[11];
    const float* W1  = (const float*)d_in[12];
    const float* b1  = (const float*)d_in[13];
    const float* W2  = (const float*)d_in[14];
    const float* b2  = (const float*)d_in[15];
    const float* W3  = (const float*)d_in[16];
    const float* b3  = (const float*)d_in[17];
    const float* lng = (const float*)d_in[18];
    const float* lnb = (const float*)d_in[19];
    const float* gcnW= (const float*)d_in[20];
    const float* gcnb= (const float*)d_in[21];
    const float* skW = (const float*)d_in[22];
    const float* skb = (const float*)d_in[23];
    const float* outg= (const float*)d_in[24];
    const float* outb= (const float*)d_in[25];

    float* ws = (float*)d_ws;
    // ---- workspace: X (SZ) + two 8M-float pools + kv buffers ≈ 95 MB ----
    float* X   = ws;                               // [B,L,N,D] activations
    float* P0  = ws + SZ;                          // 8,388,608 floats
    float* P1  = P0 + 8388608LL;                   // 8,388,608 floats
    float* KVb = P1 + 8388608LL;                   // [B,H,16,16]
    float* KSb = KVb + (long long)B_ * H_ * 256;   // [B,H,16]

    float* SKIP = (float*)d_out;                   // skip accumulates into d_out
    const long long BIGMOD = 1LL << 30;
    const int TCH = 512;                           // kv t-chunk
    const int TC_SELF  = (T_SELF  + TCH - 1) / TCH;   // 16
    const int TC_CROSS = (T_CROSS + TCH - 1) / TCH;   // 31

    hipMemsetAsync(SKIP, 0, (size_t)SZ * sizeof(float), stream);

    for (int i = 0; i < NL_; ++i) {
        const float* xc = (i == 0) ? x_in : X;

        for (int att = 0; att < 2; ++att) {        // 0=self, 1=cross
            const long long wij = (long long)(i * 2 + att) * D_ * D_;
            const long long bij = (long long)(i * 2 + att) * D_;
            const float* kvsrc = att ? mem : xc;
            const int   T      = att ? T_CROSS : T_SELF;
            const long long UB = att ? C2_ : U_;
            const int   TC     = att ? TC_CROSS : TC_SELF;

            // per-b K,V projection + partial kv reduction (K@P1, V@P1+C2, part@P0)
            for (int b = 0; b < B_; ++b) {
                const float* src = kvsrc + (long long)b * UB;
                launch_gemm(stream, src, Wk + wij, bk + bij, P1,
                            T, D_, D_, 0,0,0, D_, D_, D_, 1,1,0, 0,0, EPI_ELU1);
                launch_gemm(stream, src, Wv + wij, bv + bij, P1 + C2_,
                            T, D_, D_, 0,0,0, D_, D_, D_, 1,1,0, 0,0, EPI_NONE);
                kv_part_kernel<<<dim3(TC, H_), 256, 0, stream>>>(P1, P1 + C2_, P0, T, TCH);
                kv_reduce_kernel<<<H_, 256, 0, stream>>>(P0, KVb, KSb, b, TC);
            }
            // batched: Q proj (P0) -> combine in-place -> Wo (P1) -> add+LN -> X
            const float* qsrc = att ? ((i == 0 && att == 1) ? X : X) : xc;
            const float* resid = att ? X : xc;
            launch_gemm(stream, resid, Wq + wij, bq + bij, P0,
                        ROWS, D_, D_, 0,0,0, D_, D_, D_, 1,1,0, 0,0, EPI_ELU1);
            (void)qsrc;
            attn_out_kernel<<<ROWS / 2, dim3(128, 2), 0, stream>>>(P0, KVb, KSb, P0, T_SELF);
            launch_gemm(stream, P0, Wo + wij, bo + bij, P1,
                        ROWS, D_, D_, 0,0,0, D_, D_, D_, 1,1,0, 0,0, EPI_NONE);
            addln_kernel<<<ROWS / 4, dim3(64, 4), 0, stream>>>(
                resid, P1, lng + (i*3+att)*D_, lnb + (i*3+att)*D_, X, 0);
        }

        // ---- per-b: FFN -> As -> addln -> s1/s2 -> diffusion -> GCN -> skip ----
        for (int b = 0; b < B_; ++b) {
            float* Xb = X + (long long)b * U_;
            const float* datab = data + (long long)b * U_;
            float* FFH = P0;                        // 3,993,600
            float* Y   = P1;                        // 998,400
            float* ASb = P1 + 1048576LL;            // 2,535,000
            float* DTS = P1 + 4194304LL;            // 998,400
            float* s1  = P0;                        // after FFH is dead
            float* s2  = P0 + U_;
            float* a1  = P0 + 2 * U_;
            float* a2  = P0 + 3 * U_;

            launch_gemm(stream, Xb, W1 + (long long)i*D_*DFF_, b1 + i*DFF_, FFH,
                        T_SELF, DFF_, D_, 0,0,0, D_, DFF_, DFF_, 1,1,0, 0,0, EPI_GELU);
            launch_gemm(stream, FFH, W2 + (long long)i*DFF_*D_, b2 + i*D_, Y,
                        T_SELF, D_, DFF_, 0,0,0, DFF_, D_, D_, 1,1,0, 0,0, EPI_NONE);
            launch_gemm(stream, Y, W3 + (long long)i*D_*N_, b3 + i*N_, ASb,
                        T_SELF, N_, D_, 0,0,0, D_, N_, N_, 1,1,0, 0,0, EPI_NONE);
            addln_kernel<<<T_SELF / 4, dim3(64, 4), 0, stream>>>(
                Xb, Y, lng + (i*3+2)*D_, lnb + (i*3+2)*D_, Xb, 0);

            // s1[l][c,m] = sum_n data_b[l][n,c]*support[n,m]; s2 = s1@support
            launch_gemm(stream, datab, support, nullptr, s1,
                        D_, N_, N_, (long long)N_*D_, 0, (long long)D_*N_,
                        D_, N_, N_, L_, 1, 0, /*transA*/1, 0, EPI_NONE);
            launch_gemm(stream, s1, support, nullptr, s2,
                        D_, N_, N_, (long long)D_*N_, 0, (long long)D_*N_,
                        N_, N_, N_, L_, 1, 0, 0, 0, EPI_NONE);
            // a1 = dtm @ As ; a2 = a1 @ As   (per l)
            launch_gemm(stream, datab, ASb, nullptr, a1,
                        D_, N_, N_, (long long)N_*D_, (long long)N_*N_, (long long)D_*N_,
                        D_, N_, N_, L_, (int)BIGMOD, 0, /*transA*/1, 0, EPI_NONE);
            launch_gemm(stream, a1, ASb, nullptr, a2,
                        D_, N_, N_, (long long)D_*N_, (long long)N_*N_, (long long)D_*N_,
                        N_, N_, N_, L_, (int)BIGMOD, 0, 0, 0, EPI_NONE);

            // GCN: dts[l][n,o] = gcnb[l,o] + sum_p sum_c part_p[c,n]*gcnW[i,l,p*D+c,o]
            const float* parts[5] = { datab, s1, s2, a1, a2 };
            for (int p = 0; p < 5; ++p) {
                const float* Bp = gcnW + (long long)i * L_ * (5*D_) * D_ + (long long)p * D_ * D_;
                launch_gemm(stream, parts[p], Bp,
                            (p == 0) ? (gcnb + (long long)i * L_ * D_) : nullptr, DTS,
                            N_, D_, D_,
                            (long long)N_ * D_, (long long)(5*D_) * D_, (long long)N_ * D_,
                            (p == 0) ? D_ : N_, D_, D_,
                            L_, L_, D_,
                            (p == 0) ? 0 : 1, (p > 0) ? 1 : 0, EPI_NONE);
            }
            // skip += dts @ skW + skb
            launch_gemm(stream, DTS, skW + (long long)i*D_*D_, skb + i*D_,
                        SKIP + (long long)b * U_,
                        T_SELF, D_, D_, 0,0,0, D_, D_, D_, 1,1,0, 0, /*accum*/1, EPI_NONE);
        }
    }

    // out = LN(relu(skip)) in-place on d_out
    addln_kernel<<<ROWS / 4, dim3(64, 4), 0, stream>>>(SKIP, nullptr, outg, outb, SKIP, 1);
}

// Round 3
// 8845.786 us; speedup vs baseline: 2.2797x; 2.2797x over previous
//
#include <hip/hip_runtime.h>
#include <hip/hip_bf16.h>
#include <math.h>

// ---------------- problem constants ----------------
#define B_   8
#define L_   24
#define LP_  48
#define N_   325
#define D_   128
#define H_   8
#define NL_  3
#define DFF_ 512

typedef __attribute__((ext_vector_type(8))) short s16x8;
typedef __attribute__((ext_vector_type(4))) float f32x4;

static const int  ROWS    = B_ * L_ * N_;        // 62400
static const int  T_SELF  = L_ * N_;             // 7800
static const int  T_CROSS = LP_ * N_;            // 15600
static const long long U_ = (long long)T_SELF * D_;   // 998,400
static const long long SZ = (long long)B_ * U_;       // 7,987,200

enum { EPI_NONE = 0, EPI_ELU1 = 1, EPI_GELU = 2 };

// =====================================================================
// MFMA GEMM:  C[z][M][Nc] (=/+=) epi( sum_k A[z][m][k]*Bt[z%bmod][n][k] + bias[z%bmod][n] )
// A: f32 or bf16 (ABF), k-contiguous rows. Bt: bf16, k-contiguous rows (i.e. B^T).
// C: f32 or bf16 (OBF). 128x128 tile, 4 waves, BK=32, one mfma_16x16x32 per frag.
// =====================================================================
template<int ABF, int OBF>
__global__ __launch_bounds__(256) void mfma_gemm(
    const void* __restrict__ Av, const __hip_bfloat16* __restrict__ Bt,
    const float* __restrict__ bias, void* __restrict__ Cv,
    int M, int Nc, int K,
    long long sA, long long sB, long long sC,
    int lda, int ldb, int ldc,
    int bmod, long long sBias, int accum, int epi)
{
    const int batch = blockIdx.z;
    const int m0 = blockIdx.y * 128;
    const int n0 = blockIdx.x * 128;
    const int tid = threadIdx.x;
    const int lane = tid & 63;
    const int w = tid >> 6, wm = w >> 1, wn = w & 1;
    const int r16 = lane & 15, kb = lane >> 4;

    __shared__ __align__(16) __hip_bfloat16 shA[128][40];   // pad 40 -> 2-way max (free)
    __shared__ __align__(16) __hip_bfloat16 shB[128][40];

    const float* Af = ABF ? nullptr : ((const float*)Av + (long long)batch * sA);
    const __hip_bfloat16* Ab = ABF ? ((const __hip_bfloat16*)Av + (long long)batch * sA) : nullptr;
    const __hip_bfloat16* Bp = Bt + (long long)(batch % bmod) * sB;

    f32x4 acc[4][4];
#pragma unroll
    for (int i = 0; i < 4; ++i)
#pragma unroll
        for (int j = 0; j < 4; ++j) acc[i][j] = f32x4{0.f, 0.f, 0.f, 0.f};

    for (int k0 = 0; k0 < K; k0 += 32) {
        const bool ktail = (k0 + 32 > K);
        // ---- stage A tile [128 rows][32 k] (512 slots of 8 bf16) ----
#pragma unroll
        for (int s = 0; s < 2; ++s) {
            int slot = tid + s * 256;
            int row = slot >> 2, kg = slot & 3;
            int m = m0 + row, k = k0 + kg * 8;
            union { s16x8 v; __hip_bfloat16 h[8]; } val;
            if (m < M && !ktail) {
                if (ABF) {
                    val.v = *(const s16x8*)(Ab + (long long)m * lda + k);
                } else {
                    const float* p = Af + (long long)m * lda + k;
                    f32x4 v0 = *(const f32x4*)p, v1 = *(const f32x4*)(p + 4);
#pragma unroll
                    for (int e = 0; e < 4; ++e) {
                        val.h[e]     = __float2bfloat16(v0[e]);
                        val.h[e + 4] = __float2bfloat16(v1[e]);
                    }
                }
            } else {
#pragma unroll
                for (int e = 0; e < 8; ++e) {
                    float f = 0.f;
                    if (m < M && (k + e) < K)
                        f = ABF ? __bfloat162float(Ab[(long long)m * lda + k + e])
                                : Af[(long long)m * lda + k + e];
                    val.h[e] = __float2bfloat16(f);
                }
            }
            *(s16x8*)&shA[row][kg * 8] = val.v;
        }
        // ---- stage Bt tile [128 n-rows][32 k] ----
#pragma unroll
        for (int s = 0; s < 2; ++s) {
            int slot = tid + s * 256;
            int row = slot >> 2, kg = slot & 3;
            int n = n0 + row, k = k0 + kg * 8;
            union { s16x8 v; __hip_bfloat16 h[8]; } val;
            if (n < Nc && !ktail) {
                val.v = *(const s16x8*)(Bp + (long long)n * ldb + k);
            } else {
#pragma unroll
                for (int e = 0; e < 8; ++e) {
                    float f = 0.f;
                    if (n < Nc && (k + e) < K)
                        f = __bfloat162float(Bp[(long long)n * ldb + k + e]);
                    val.h[e] = __float2bfloat16(f);
                }
            }
            *(s16x8*)&shB[row][kg * 8] = val.v;
        }
        __syncthreads();

        s16x8 av[4], bv[4];
#pragma unroll
        for (int mi = 0; mi < 4; ++mi)
            av[mi] = *(const s16x8*)&shA[wm * 64 + mi * 16 + r16][kb * 8];
#pragma unroll
        for (int ni = 0; ni < 4; ++ni)
            bv[ni] = *(const s16x8*)&shB[wn * 64 + ni * 16 + r16][kb * 8];
#pragma unroll
        for (int mi = 0; mi < 4; ++mi)
#pragma unroll
            for (int ni = 0; ni < 4; ++ni)
                acc[mi][ni] = __builtin_amdgcn_mfma_f32_16x16x32_bf16(
                    av[mi], bv[ni], acc[mi][ni], 0, 0, 0);
        __syncthreads();
    }

    const float* bp = bias ? (bias + (long long)(batch % bmod) * sBias) : nullptr;
    float* Cf = OBF ? nullptr : ((float*)Cv + (long long)batch * sC);
    __hip_bfloat16* Cb = OBF ? ((__hip_bfloat16*)Cv + (long long)batch * sC) : nullptr;
#pragma unroll
    for (int mi = 0; mi < 4; ++mi) {
#pragma unroll
        for (int ni = 0; ni < 4; ++ni) {
#pragma unroll
            for (int rr = 0; rr < 4; ++rr) {
                int m = m0 + wm * 64 + mi * 16 + kb * 4 + rr;   // D row = (lane>>4)*4+reg
                int n = n0 + wn * 64 + ni * 16 + r16;           // D col = lane&15
                if (m < M && n < Nc) {
                    float v = acc[mi][ni][rr];
                    if (bp) v += bp[n];
                    if (epi == EPI_ELU1)      v = (v > 0.f) ? (v + 1.f) : expf(v);
                    else if (epi == EPI_GELU) v = 0.5f * v * (1.f + erff(v * 0.70710678118654752f));
                    long long ci = (long long)m * ldc + n;
                    if (OBF) Cb[ci] = __float2bfloat16(v);
                    else { if (accum) Cf[ci] += v; else Cf[ci] = v; }
                }
            }
        }
    }
}

static inline void gemm(hipStream_t st, int abf, int obf,
                        const void* A, const __hip_bfloat16* Bt, const float* bias, void* C,
                        int M, int Nc, int K,
                        long long sA, long long sB, long long sC,
                        int lda, int ldb, int ldc,
                        int batches, int bmod, long long sBias, int accum, int epi)
{
    dim3 g((Nc + 127) / 128, (M + 127) / 128, batches);
    if (abf) {
        if (obf) mfma_gemm<1,1><<<g,256,0,st>>>(A,Bt,bias,C,M,Nc,K,sA,sB,sC,lda,ldb,ldc,bmod,sBias,accum,epi);
        else     mfma_gemm<1,0><<<g,256,0,st>>>(A,Bt,bias,C,M,Nc,K,sA,sB,sC,lda,ldb,ldc,bmod,sBias,accum,epi);
    } else {
        if (obf) mfma_gemm<0,1><<<g,256,0,st>>>(A,Bt,bias,C,M,Nc,K,sA,sB,sC,lda,ldb,ldc,bmod,sBias,accum,epi);
        else     mfma_gemm<0,0><<<g,256,0,st>>>(A,Bt,bias,C,M,Nc,K,sA,sB,sC,lda,ldb,ldc,bmod,sBias,accum,epi);
    }
}

// =====================================================================
// transpose-convert: dst[z][c][r] = src[z][r][c] (bf16 out, zero-pad r in [R,ldd))
// =====================================================================
template<int SBF>
__global__ __launch_bounds__(256) void tconv(
    const void* __restrict__ srcv, __hip_bfloat16* __restrict__ dst,
    int R, int C, int lds_, long long sS, int ldd, long long sD)
{
    const int bz = blockIdx.z;
    const float* sf = SBF ? nullptr : ((const float*)srcv + (long long)bz * sS);
    const __hip_bfloat16* sb = SBF ? ((const __hip_bfloat16*)srcv + (long long)bz * sS) : nullptr;
    __hip_bfloat16* dp = dst + (long long)bz * sD;
    __shared__ float t[32][33];
    const int r0 = blockIdx.x * 32, c0 = blockIdx.y * 32;
    for (int i = threadIdx.y; i < 32; i += 8) {
        int r = r0 + i, c = c0 + threadIdx.x;
        float v = 0.f;
        if (r < R && c < C)
            v = SBF ? __bfloat162float(sb[(long long)r * lds_ + c]) : sf[(long long)r * lds_ + c];
        t[i][threadIdx.x] = v;
    }
    __syncthreads();
    for (int i = threadIdx.y; i < 32; i += 8) {
        int c = c0 + i, r = r0 + threadIdx.x;
        if (c < C && r < ldd) dp[(long long)c * ldd + r] = __float2bfloat16(t[threadIdx.x][i]);
    }
}

// ---------------- linear attention: partial kv over 512-token chunks (bf16 in)
__global__ __launch_bounds__(256) void kv_part_bf16(
    const __hip_bfloat16* __restrict__ kp, const __hip_bfloat16* __restrict__ vp,
    float* __restrict__ part, int T, int TC)
{
    const int z = blockIdx.z, h = blockIdx.y, tc = blockIdx.x;
    kp += (long long)z * T * D_;
    vp += (long long)z * T * D_;
    const int t0 = tc * 512;
    const int tend = min(T, t0 + 512);
    const int tid = threadIdx.x;
    const int e = tid >> 4, d = tid & 15;
    __shared__ float sk[64][16];
    __shared__ float sv[64][16];
    float acc = 0.f, asum = 0.f;
    for (int tb = t0; tb < tend; tb += 64) {
#pragma unroll
        for (int r = 0; r < 4; ++r) {
            int idx = tid + r * 256, tt = idx >> 4, c = idx & 15;
            int t = tb + tt;
            float kk = 0.f, vv = 0.f;
            if (t < tend) {
                long long gi = (long long)t * D_ + h * 16 + c;
                kk = __bfloat162float(kp[gi]);
                vv = __bfloat162float(vp[gi]);
            }
            sk[tt][c] = kk; sv[tt][c] = vv;
        }
        __syncthreads();
#pragma unroll 8
        for (int tt = 0; tt < 64; ++tt) {
            float ke = sk[tt][e];
            acc  = fmaf(ke, sv[tt][d], acc);
            asum += ke;
        }
        __syncthreads();
    }
    float* pp = part + (((long long)z * TC + tc) * H_ + h) * 272;
    pp[e * 16 + d] = acc;
    if (d == 0) pp[256 + e] = asum;
}

__global__ __launch_bounds__(256) void kv_reduce2(
    const float* __restrict__ part, float* __restrict__ kv,
    float* __restrict__ ksum, int b0, int TC)
{
    const int h = blockIdx.x, z = blockIdx.y, b = b0 + z;
    const float* pz = part + (long long)z * TC * H_ * 272;
    const int tid = threadIdx.x, e = tid >> 4, d = tid & 15;
    float acc = 0.f;
    for (int tc = 0; tc < TC; ++tc) acc += pz[((long long)tc * H_ + h) * 272 + e * 16 + d];
    kv[((long long)(b * H_ + h) * 16 + e) * 16 + d] = acc;
    if (d == 0) {
        float s = 0.f;
        for (int tc = 0; tc < TC; ++tc) s += pz[((long long)tc * H_ + h) * 272 + 256 + e];
        ksum[(b * H_ + h) * 16 + e] = s;
    }
}

// ---------------- attention combine (in-place safe) ----------
__global__ __launch_bounds__(256) void attn_out_kernel(
    const float* __restrict__ qp, const float* __restrict__ kv,
    const float* __restrict__ ksum, float* __restrict__ out, int SperB, int b0)
{
    const int row = blockIdx.x * 2 + threadIdx.y;
    const int o = threadIdx.x;
    const int h = o >> 4, dp = o & 15;
    __shared__ float sq[2][D_];
    const int b = b0 + row / SperB;
    sq[threadIdx.y][o] = qp[(long long)row * D_ + o];
    __syncthreads();
    const float* ks  = ksum + (b * H_ + h) * 16;
    const float* kvp = kv + (long long)(b * H_ + h) * 256 + dp;
    float den = 1e-6f, acc = 0.f;
#pragma unroll
    for (int e = 0; e < 16; ++e) {
        float q = sq[threadIdx.y][h * 16 + e];
        den = fmaf(q, ks[e], den);
        acc = fmaf(q, kvp[e * 16], acc);
    }
    out[(long long)row * D_ + o] = acc / den;
}

// ---------------- fused (residual|relu) + LayerNorm (in-place safe)
__global__ __launch_bounds__(256) void addln_kernel(
    const float* __restrict__ xin, const float* __restrict__ addend,
    const float* __restrict__ g, const float* __restrict__ beta,
    float* __restrict__ outp, int relu_mode)
{
    const int row = blockIdx.x * 4 + threadIdx.y;
    const int lane = threadIdx.x;
    const long long base = (long long)row * D_;
    float v0 = xin[base + lane], v1 = xin[base + lane + 64];
    if (addend) { v0 += addend[base + lane]; v1 += addend[base + lane + 64]; }
    if (relu_mode) { v0 = fmaxf(v0, 0.f); v1 = fmaxf(v1, 0.f); }
    float s = v0 + v1;
#pragma unroll
    for (int off = 32; off; off >>= 1) s += __shfl_xor(s, off);
    const float mean = s * (1.f / 128.f);
    const float c0 = v0 - mean, c1 = v1 - mean;
    float vs = c0 * c0 + c1 * c1;
#pragma unroll
    for (int off = 32; off; off >>= 1) vs += __shfl_xor(vs, off);
    const float rstd = rsqrtf(vs * (1.f / 128.f) + 1e-5f);
    outp[base + lane]      = c0 * rstd * g[lane] + beta[lane];
    outp[base + lane + 64] = c1 * rstd * g[lane + 64] + beta[lane + 64];
}

// ---------------- driver ----------------
extern "C" void kernel_launch(void* const* d_in, const int* in_sizes, int n_in,
                              void* d_out, int out_size, void* d_ws, size_t ws_size,
                              hipStream_t stream)
{
    (void)in_sizes; (void)n_in; (void)out_size; (void)ws_size;

    const float* x_in    = (const float*)d_in[0];
    const float* mem     = (const float*)d_in[1];
    const float* data    = (const float*)d_in[2];
    const float* support = (const float*)d_in[3];
    const float* Wq  = (const float*)d_in[4];
    const float* bq  = (const float*)d_in[5];
    const float* Wk  = (const float*)d_in[6];
    const float* bk  = (const float*)d_in[7];
    const float* Wv  = (const float*)d_in[8];
    const float* bv  = (const float*)d_in[9];
    const float* Wo  = (const float*)d_in[10];
    const float* bo  = (const float*)d_in[11];
    const float* W1  = (const float*)d_in[12];
    const float* b1  = (const float*)d_in[13];
    const float* W2  = (const float*)d_in[14];
    const float* b2  = (const float*)d_in[15];
    const float* W3  = (const float*)d_in[16];
    const float* b3  = (const float*)d_in[17];
    const float* lng = (const float*)d_in[18];
    const float* lnb = (const float*)d_in[19];
    const float* gcnW= (const float*)d_in[20];
    const float* gcnb= (const float*)d_in[21];
    const float* skW = (const float*)d_in[22];
    const float* skb = (const float*)d_in[23];
    const float* outg= (const float*)d_in[24];
    const float* outb= (const float*)d_in[25];

    float* ws = (float*)d_ws;
    // ---- workspace (floats): X | POOL(12M) | WBF(bf16) | KVb/KSb  ≈ 94.5 MB ----
    float* X    = ws;                                   // 7,987,200
    float* POOL = ws + 8000000LL;                       // 12,000,000 floats (48MB)
    __hip_bfloat16* WBF = (__hip_bfloat16*)(ws + 20000000LL);
    float* KVb  = ws + 23600000LL;                      // [B][H][16][16]
    float* KSb  = KVb + (long long)B_ * H_ * 256;       // [B][H][16]

    __hip_bfloat16* WqT  = WBF + 0;        // [6][128][128]
    __hip_bfloat16* WkT  = WBF + 98304;
    __hip_bfloat16* WvT  = WBF + 196608;
    __hip_bfloat16* WoT  = WBF + 294912;
    __hip_bfloat16* W1T  = WBF + 393216;   // [3][512][128]
    __hip_bfloat16* W2T  = WBF + 589824;   // [3][128][512]
    __hip_bfloat16* W3T  = WBF + 786432;   // [3][325][128]
    __hip_bfloat16* skWT = WBF + 911232;   // [3][128][128]
    __hip_bfloat16* SupT = WBF + 960384;   // [325][328]
    __hip_bfloat16* gWT  = WBF + 1066984;  // [3][24][5][128][128]

    float* SKIP = (float*)d_out;
    const int BIG = 1 << 30;
    dim3 blk(32, 8);
    auto TG = [](int ldd, int C, int b) { return dim3((ldd + 31) / 32, (C + 31) / 32, b); };

    // ---- prepass: weights -> transposed bf16 ----
    tconv<0><<<TG(128,128,6),  blk,0,stream>>>(Wq,  WqT, 128,128,128, 16384, 128, 16384);
    tconv<0><<<TG(128,128,6),  blk,0,stream>>>(Wk,  WkT, 128,128,128, 16384, 128, 16384);
    tconv<0><<<TG(128,128,6),  blk,0,stream>>>(Wv,  WvT, 128,128,128, 16384, 128, 16384);
    tconv<0><<<TG(128,128,6),  blk,0,stream>>>(Wo,  WoT, 128,128,128, 16384, 128, 16384);
    tconv<0><<<TG(128,512,3),  blk,0,stream>>>(W1,  W1T, 128,512,512, 65536, 128, 65536);
    tconv<0><<<TG(512,128,3),  blk,0,stream>>>(W2,  W2T, 512,128,128, 65536, 512, 65536);
    tconv<0><<<TG(128,325,3),  blk,0,stream>>>(W3,  W3T, 128,325,325, 41600, 128, 41600);
    tconv<0><<<TG(128,128,3),  blk,0,stream>>>(skW, skWT,128,128,128, 16384, 128, 16384);
    tconv<0><<<TG(328,325,1),  blk,0,stream>>>(support, SupT, 325,325,325, 0, 328, 0);
    tconv<0><<<TG(128,128,360),blk,0,stream>>>(gcnW, gWT, 128,128,128, 16384, 128, 16384);
    hipMemsetAsync(SKIP, 0, (size_t)SZ * sizeof(float), stream);

    for (int i = 0; i < NL_; ++i) {
        const float* xc = (i == 0) ? x_in : X;

        for (int att = 0; att < 2; ++att) {
            const int wi = i * 2 + att;
            const __hip_bfloat16 *wqp = WqT + (long long)wi*16384, *wkp = WkT + (long long)wi*16384;
            const __hip_bfloat16 *wvp = WvT + (long long)wi*16384, *wop = WoT + (long long)wi*16384;
            const float *bqp = bq + wi*128, *bkp = bk + wi*128, *bvp = bv + wi*128, *bop = bo + wi*128;
            const float* kvsrc = att ? mem : xc;
            const int T  = att ? T_CROSS : T_SELF;
            const int TC = (T + 511) / 512;
            const float* resid = att ? X : xc;

            for (int c = 0; c < 2; ++c) {              // 4-batch chunks
                const int b0 = c * 4;
                __hip_bfloat16* Kbf = (__hip_bfloat16*)POOL;
                __hip_bfloat16* Vbf = (__hip_bfloat16*)(POOL + 4000000LL);
                float* part = POOL + 8000000LL;
                const float* ksrc = kvsrc + (long long)b0 * T * D_;
                gemm(stream,0,1, ksrc, wkp, bkp, Kbf, 4*T,128,128, 0,0,0, 128,128,128, 1,1,0, 0, EPI_ELU1);
                gemm(stream,0,1, ksrc, wvp, bvp, Vbf, 4*T,128,128, 0,0,0, 128,128,128, 1,1,0, 0, EPI_NONE);
                kv_part_bf16<<<dim3(TC,H_,4),256,0,stream>>>(Kbf, Vbf, part, T, TC);
                kv_reduce2<<<dim3(H_,4),256,0,stream>>>(part, KVb, KSb, b0, TC);

                float* Qp = POOL;
                float* Ob = POOL + 4000000LL;
                const float* rz = resid + (long long)b0 * U_;
                gemm(stream,0,0, rz, wqp, bqp, Qp, 4*T_SELF,128,128, 0,0,0, 128,128,128, 1,1,0, 0, EPI_ELU1);
                attn_out_kernel<<<dim3(4*T_SELF/2), dim3(128,2),0,stream>>>(Qp, KVb, KSb, Qp, T_SELF, b0);
                gemm(stream,0,0, Qp, wop, bop, Ob, 4*T_SELF,128,128, 0,0,0, 128,128,128, 1,1,0, 0, EPI_NONE);
                addln_kernel<<<4*T_SELF/4, dim3(64,4),0,stream>>>(
                    rz, Ob, lng + (i*3+att)*128, lnb + (i*3+att)*128, X + (long long)b0 * U_, 0);
            }
        }

        // ---- FFN + adjacency + diffusion + GCN + skip, 2-batch chunks (48 z-slices) ----
        for (int c = 0; c < 4; ++c) {
            const int b0 = c * 2;
            float* Xb = X + (long long)b0 * U_;
            const float* datab = data + (long long)b0 * U_;

            __hip_bfloat16* FFH  = (__hip_bfloat16*)POOL;                  // [15600][512] bf16
            float* Y  = POOL + 4000000LL;                                  // [15600][128] f32
            float* As = POOL + 6000000LL;                                  // [15600][325] f32
            __hip_bfloat16* AsT  = (__hip_bfloat16*)POOL;                  // [48][325][328]
            __hip_bfloat16* DTb  = (__hip_bfloat16*)(POOL + 2600000LL);    // [48][128][328]
            __hip_bfloat16* s1t  = (__hip_bfloat16*)(POOL + 3700000LL);    // [48][325][128]
            __hip_bfloat16* s1ct = (__hip_bfloat16*)(POOL + 4800000LL);    // [48][128][328]
            __hip_bfloat16* s2t  = (__hip_bfloat16*)(POOL + 5900000LL);    // [48][325][128]
            __hip_bfloat16* a1t  = (__hip_bfloat16*)(POOL + 7000000LL);    // [48][325][128]
            __hip_bfloat16* a1ct = (__hip_bfloat16*)(POOL + 8100000LL);    // [48][128][328]
            __hip_bfloat16* a2t  = (__hip_bfloat16*)(POOL + 9200000LL);    // [48][325][128]

            gemm(stream,0,1, Xb, W1T + (long long)i*65536, b1 + i*512, FFH,
                 2*T_SELF, 512, 128, 0,0,0, 128,128,512, 1,1,0, 0, EPI_GELU);
            gemm(stream,1,0, FFH, W2T + (long long)i*65536, b2 + i*128, Y,
                 2*T_SELF, 128, 512, 0,0,0, 512,512,128, 1,1,0, 0, EPI_NONE);
            gemm(stream,0,0, Y, W3T + (long long)i*41600, b3 + i*325, As,
                 2*T_SELF, 325, 128, 0,0,0, 128,128,325, 1,1,0, 0, EPI_NONE);
            addln_kernel<<<2*T_SELF/4, dim3(64,4),0,stream>>>(
                Xb, Y, lng + (i*3+2)*128, lnb + (i*3+2)*128, Xb, 0);

            tconv<0><<<TG(328,325,48),blk,0,stream>>>(As, AsT, 325,325,325, 105625, 328, 106600);
            tconv<0><<<TG(328,128,48),blk,0,stream>>>(datab, DTb, 325,128,128, 41600, 328, 41984);
            gemm(stream,1,1, SupT, DTb, nullptr, s1t, 325,128,328, 0,41984,41600, 328,328,128, 48,BIG,0, 0, EPI_NONE);
            tconv<1><<<TG(328,128,48),blk,0,stream>>>(s1t, s1ct, 325,128,128, 41600, 328, 41984);
            gemm(stream,1,1, SupT, s1ct, nullptr, s2t, 325,128,328, 0,41984,41600, 328,328,128, 48,BIG,0, 0, EPI_NONE);
            gemm(stream,1,1, AsT, DTb, nullptr, a1t, 325,128,328, 106600,41984,41600, 328,328,128, 48,BIG,0, 0, EPI_NONE);
            tconv<1><<<TG(328,128,48),blk,0,stream>>>(a1t, a1ct, 325,128,128, 41600, 328, 41984);
            gemm(stream,1,1, AsT, a1ct, nullptr, a2t, 325,128,328, 106600,41984,41600, 328,328,128, 48,BIG,0, 0, EPI_NONE);

            float* dts = POOL;                                             // [48][325][128] f32
            const __hip_bfloat16* gbase = gWT + (long long)i * 1966080;
            for (int p = 0; p < 5; ++p) {
                const void* Ap = (p==0) ? (const void*)datab :
                                 (p==1) ? (const void*)s1t : (p==2) ? (const void*)s2t :
                                 (p==3) ? (const void*)a1t : (const void*)a2t;
                gemm(stream, p?1:0, 0, Ap, gbase + p*16384,
                     (p==0) ? (gcnb + (long long)i*24*128) : nullptr, dts,
                     325,128,128, 41600, 5*16384, 41600, 128,128,128,
                     48, 24, 128, p?1:0, EPI_NONE);
            }
            gemm(stream,0,0, dts, skWT + (long long)i*16384, skb + i*128, SKIP + (long long)b0*U_,
                 325,128,128, 41600,0,41600, 128,128,128, 48,1,0, 1, EPI_NONE);
        }
    }

    addln_kernel<<<ROWS/4, dim3(64,4),0,stream>>>(SKIP, nullptr, outg, outb, SKIP, 1);
}

// Round 4
// 7323.381 us; speedup vs baseline: 2.7536x; 1.2079x over previous
//
#include <hip/hip_runtime.h>
#include <hip/hip_bf16.h>
#include <math.h>

// ---------------- problem constants ----------------
#define B_   8
#define L_   24
#define LP_  48
#define N_   325
#define D_   128
#define H_   8
#define NL_  3
#define DFF_ 512

typedef __attribute__((ext_vector_type(8))) short s16x8;
typedef __attribute__((ext_vector_type(4))) float f32x4;
typedef __hip_bfloat16 bf16;

static const int  ROWS    = B_ * L_ * N_;        // 62400
static const int  T_SELF  = L_ * N_;             // 7800
static const int  T_CROSS = LP_ * N_;            // 15600
static const long long U_ = (long long)T_SELF * D_;   // 998,400
static const long long SZ = (long long)B_ * U_;       // 7,987,200

enum { EPI_NONE = 0, EPI_ELU1 = 1, EPI_GELU = 2 };

struct MOut { void* d[3]; long long sC[3]; int ldc_[3]; int flg[3]; };  // flg = obf | (epi<<1)

__device__ __forceinline__ float apply_epi(float v, int epi) {
    if (epi == EPI_ELU1) return (v > 0.f) ? (v + 1.f) : expf(v);
    if (epi == EPI_GELU) return 0.5f * v * (1.f + erff(v * 0.70710678118654752f));
    return v;
}

// =====================================================================
// MFMA GEMM, 128x128 tile, 4 waves, BK=64. REQUIRES K % 64 == 0.
// C[z][M][Nc] (=/+=) epi( sum_k A[z][m][k] * Bt[z%bmod][n][k] + bias[z%bmod][n] )
// MULTI: per-128-col-block output spec (dst/ldc/sC/obf/epi from MOut).
// =====================================================================
template<int ABF, int MULTI>
__global__ __launch_bounds__(256) void gk(
    const void* __restrict__ Av, const bf16* __restrict__ Bt,
    const float* __restrict__ bias, void* __restrict__ Cv, MOut mo,
    int M, int Nc, int K,
    long long sA, long long sB, long long sC,
    int lda, int ldb, int ldc,
    int bmod, long long sBias, int accum, int epi, int obf)
{
    const int batch = blockIdx.z;
    const int m0 = blockIdx.y * 128, n0 = blockIdx.x * 128;
    const int tid = threadIdx.x, lane = tid & 63;
    const int w = tid >> 6, wm = w >> 1, wn = w & 1;
    const int r16 = lane & 15, kb = lane >> 4;

    __shared__ bf16 shA[128][72];   // 72 = 64 + 8 pad -> max 2-way bank alias (free)
    __shared__ bf16 shB[128][72];

    const float* Af = ABF ? nullptr : ((const float*)Av + (long long)batch * sA);
    const bf16*  Ab = ABF ? ((const bf16*)Av + (long long)batch * sA) : nullptr;
    const bf16*  Bp = Bt + (long long)(batch % bmod) * sB;

    f32x4 acc[4][4];
#pragma unroll
    for (int i = 0; i < 4; ++i)
#pragma unroll
        for (int j = 0; j < 4; ++j) acc[i][j] = f32x4{0.f, 0.f, 0.f, 0.f};

    for (int k0 = 0; k0 < K; k0 += 64) {
        // stage A tile [128 m][64 k]: 1024 slots of 8 bf16, 4 per thread
#pragma unroll
        for (int s = 0; s < 4; ++s) {
            int slot = tid + s * 256;
            int row = slot >> 3, kg = slot & 7;
            int m = m0 + row, k = k0 + kg * 8;
            union { s16x8 v; bf16 h[8]; } val;
            if (m < M) {
                if (ABF) {
                    val.v = *(const s16x8*)(Ab + (long long)m * lda + k);
                } else {
                    f32x4 v0 = *(const f32x4*)(Af + (long long)m * lda + k);
                    f32x4 v1 = *(const f32x4*)(Af + (long long)m * lda + k + 4);
#pragma unroll
                    for (int e = 0; e < 4; ++e) {
                        val.h[e]     = __float2bfloat16(v0[e]);
                        val.h[e + 4] = __float2bfloat16(v1[e]);
                    }
                }
            } else {
#pragma unroll
                for (int e = 0; e < 8; ++e) val.h[e] = __float2bfloat16(0.f);
            }
            *(s16x8*)&shA[row][kg * 8] = val.v;
        }
        // stage B tile [128 n][64 k]
#pragma unroll
        for (int s = 0; s < 4; ++s) {
            int slot = tid + s * 256;
            int row = slot >> 3, kg = slot & 7;
            int n = n0 + row, k = k0 + kg * 8;
            union { s16x8 v; bf16 h[8]; } val;
            if (n < Nc) {
                val.v = *(const s16x8*)(Bp + (long long)n * ldb + k);
            } else {
#pragma unroll
                for (int e = 0; e < 8; ++e) val.h[e] = __float2bfloat16(0.f);
            }
            *(s16x8*)&shB[row][kg * 8] = val.v;
        }
        __syncthreads();
#pragma unroll
        for (int kh = 0; kh < 2; ++kh) {
            s16x8 av[4], bv[4];
#pragma unroll
            for (int mi = 0; mi < 4; ++mi)
                av[mi] = *(const s16x8*)&shA[wm * 64 + mi * 16 + r16][kh * 32 + kb * 8];
#pragma unroll
            for (int ni = 0; ni < 4; ++ni)
                bv[ni] = *(const s16x8*)&shB[wn * 64 + ni * 16 + r16][kh * 32 + kb * 8];
#pragma unroll
            for (int mi = 0; mi < 4; ++mi)
#pragma unroll
                for (int ni = 0; ni < 4; ++ni)
                    acc[mi][ni] = __builtin_amdgcn_mfma_f32_16x16x32_bf16(
                        av[mi], bv[ni], acc[mi][ni], 0, 0, 0);
        }
        __syncthreads();
    }

    // epilogue
    int epi_ = epi, obf_ = obf, ldcc = ldc;
    long long scc = sC;
    void* dst = Cv;
    if (MULTI) {
        const int bx = blockIdx.x;
        epi_ = mo.flg[bx] >> 1; obf_ = mo.flg[bx] & 1;
        ldcc = mo.ldc_[bx]; scc = mo.sC[bx]; dst = mo.d[bx];
    }
    float* Cf = (float*)dst + (long long)batch * scc;
    bf16*  Cb = (bf16*)dst  + (long long)batch * scc;
    const float* bp = bias ? (bias + (long long)(batch % bmod) * sBias) : nullptr;
#pragma unroll
    for (int mi = 0; mi < 4; ++mi) {
#pragma unroll
        for (int ni = 0; ni < 4; ++ni) {
#pragma unroll
            for (int rr = 0; rr < 4; ++rr) {
                int m = m0 + wm * 64 + mi * 16 + kb * 4 + rr;
                int ln = wn * 64 + ni * 16 + r16;
                int n = n0 + ln;
                if (m >= M || n >= Nc) continue;
                float v = acc[mi][ni][rr];
                if (bp) v += bp[n];
                v = apply_epi(v, epi_);
                long long ci = (long long)m * ldcc + (MULTI ? ln : n);
                if (obf_) Cb[ci] = __float2bfloat16(v);
                else { if (accum) Cf[ci] += v; else Cf[ci] = v; }
            }
        }
    }
}

static inline void gemm1(hipStream_t st, int abf, const void* A, const bf16* Bt,
                         const float* bias, void* C,
                         int M, int Nc, int K,
                         long long sA, long long sB, long long sC,
                         int lda, int ldb, int ldc,
                         int z, int bmod, long long sBias, int accum, int epi, int obf)
{
    dim3 g((Nc + 127) / 128, (M + 127) / 128, z);
    MOut mo{};
    if (abf) gk<1,0><<<g,256,0,st>>>(A,Bt,bias,C,mo,M,Nc,K,sA,sB,sC,lda,ldb,ldc,bmod,sBias,accum,epi,obf);
    else     gk<0,0><<<g,256,0,st>>>(A,Bt,bias,C,mo,M,Nc,K,sA,sB,sC,lda,ldb,ldc,bmod,sBias,accum,epi,obf);
}

static inline void gemm3(hipStream_t st, const void* A, const bf16* Bt,
                         const float* bias, const MOut& mo, int M, int Nc, int K,
                         int lda, int ldb)
{
    dim3 g(Nc / 128, (M + 127) / 128, 1);
    gk<0,1><<<g,256,0,st>>>(A,Bt,bias,nullptr,mo,M,Nc,K,0,0,0,lda,ldb,0,1,0,0,0,0);
}

// =====================================================================
// transpose-convert: dst[z][c][r] = src[z][r][c], bf16 out, zero r in [R,ldd)
// =====================================================================
template<int SBF>
__global__ __launch_bounds__(256) void tconv(
    const void* __restrict__ srcv, bf16* __restrict__ dst,
    int R, int C, int lds_, long long sS, int ldd, long long sD)
{
    const int bz = blockIdx.z;
    const float* sf = SBF ? nullptr : ((const float*)srcv + (long long)bz * sS);
    const bf16* sb = SBF ? ((const bf16*)srcv + (long long)bz * sS) : nullptr;
    bf16* dp = dst + (long long)bz * sD;
    __shared__ float t[32][33];
    const int r0 = blockIdx.x * 32, c0 = blockIdx.y * 32;
    for (int i = threadIdx.y; i < 32; i += 8) {
        int r = r0 + i, c = c0 + threadIdx.x;
        float v = 0.f;
        if (r < R && c < C)
            v = SBF ? __bfloat162float(sb[(long long)r * lds_ + c]) : sf[(long long)r * lds_ + c];
        t[i][threadIdx.x] = v;
    }
    __syncthreads();
    for (int i = threadIdx.y; i < 32; i += 8) {
        int c = c0 + i, r = r0 + threadIdx.x;
        if (c < C && r < ldd) dp[(long long)c * ldd + r] = __float2bfloat16(t[threadIdx.x][i]);
    }
}

// strided f32 -> bf16 convert (rows*C total elems)
__global__ __launch_bounds__(256) void conv_k(
    const float* __restrict__ src, bf16* __restrict__ dst,
    long long total, int C, int slds, int dldd)
{
    for (long long idx = blockIdx.x * 256LL + threadIdx.x; idx < total;
         idx += (long long)gridDim.x * 256) {
        long long r = idx / C; int c = (int)(idx - r * C);
        dst[r * dldd + c] = __float2bfloat16(src[r * slds + c]);
    }
}

// skb2[l2][o] = skb[i][o] + sum_c gcnb[l2][c] * skW[i][c][o]   (l2 = i*24+l)
__global__ __launch_bounds__(128) void skb2_k(
    const float* __restrict__ gcnb, const float* __restrict__ skW,
    const float* __restrict__ skb, float* __restrict__ skb2)
{
    const int l2 = blockIdx.x, o = threadIdx.x, i = l2 / 24;
    float acc = skb[i * 128 + o];
    for (int c = 0; c < 128; ++c)
        acc += gcnb[l2 * 128 + c] * skW[i * 16384 + c * 128 + o];
    skb2[l2 * 128 + o] = acc;
}

// bqkv[wi][0:128]=bq, [128:256]=bk, [256:384]=bv
__global__ __launch_bounds__(384) void cbias_k(
    const float* __restrict__ bq, const float* __restrict__ bk,
    const float* __restrict__ bv, float* __restrict__ bqkv)
{
    const int wi = blockIdx.x, j = threadIdx.x;
    float v = (j < 128) ? bq[wi * 128 + j] : (j < 256) ? bk[wi * 128 + j - 128] : bv[wi * 128 + j - 256];
    bqkv[wi * 384 + j] = v;
}

// ---------------- linear attention partial kv ----------------
__global__ __launch_bounds__(256) void kv_part_bf16(
    const bf16* __restrict__ kp, const bf16* __restrict__ vp,
    float* __restrict__ part, int T, int TC)
{
    const int z = blockIdx.z, h = blockIdx.y, tc = blockIdx.x;
    kp += (long long)z * T * D_;
    vp += (long long)z * T * D_;
    const int t0 = tc * 512;
    const int tend = min(T, t0 + 512);
    const int tid = threadIdx.x;
    const int e = tid >> 4, d = tid & 15;
    __shared__ float sk[64][16];
    __shared__ float sv[64][16];
    float acc = 0.f, asum = 0.f;
    for (int tb = t0; tb < tend; tb += 64) {
#pragma unroll
        for (int r = 0; r < 4; ++r) {
            int idx = tid + r * 256, tt = idx >> 4, c = idx & 15;
            int t = tb + tt;
            float kk = 0.f, vv = 0.f;
            if (t < tend) {
                long long gi = (long long)t * D_ + h * 16 + c;
                kk = __bfloat162float(kp[gi]);
                vv = __bfloat162float(vp[gi]);
            }
            sk[tt][c] = kk; sv[tt][c] = vv;
        }
        __syncthreads();
#pragma unroll 8
        for (int tt = 0; tt < 64; ++tt) {
            float ke = sk[tt][e];
            acc  = fmaf(ke, sv[tt][d], acc);
            asum += ke;
        }
        __syncthreads();
    }
    float* pp = part + (((long long)z * TC + tc) * H_ + h) * 272;
    pp[e * 16 + d] = acc;
    if (d == 0) pp[256 + e] = asum;
}

__global__ __launch_bounds__(256) void kv_reduce2(
    const float* __restrict__ part, float* __restrict__ kv,
    float* __restrict__ ksum, int b0, int TC)
{
    const int h = blockIdx.x, z = blockIdx.y, b = b0 + z;
    const float* pz = part + (long long)z * TC * H_ * 272;
    const int tid = threadIdx.x, e = tid >> 4, d = tid & 15;
    float acc = 0.f;
    for (int tc = 0; tc < TC; ++tc) acc += pz[((long long)tc * H_ + h) * 272 + e * 16 + d];
    kv[((long long)(b * H_ + h) * 16 + e) * 16 + d] = acc;
    if (d == 0) {
        float s = 0.f;
        for (int tc = 0; tc < TC; ++tc) s += pz[((long long)tc * H_ + h) * 272 + 256 + e];
        ksum[(b * H_ + h) * 16 + e] = s;
    }
}

// ---------------- attention combine (in-place safe) ----------
__global__ __launch_bounds__(256) void attn_out_kernel(
    const float* __restrict__ qp, const float* __restrict__ kv,
    const float* __restrict__ ksum, float* __restrict__ out, int SperB, int b0)
{
    const int row = blockIdx.x * 2 + threadIdx.y;
    const int o = threadIdx.x;
    const int h = o >> 4, dp = o & 15;
    __shared__ float sq[2][D_];
    const int b = b0 + row / SperB;
    sq[threadIdx.y][o] = qp[(long long)row * D_ + o];
    __syncthreads();
    const float* ks  = ksum + (b * H_ + h) * 16;
    const float* kvp = kv + (long long)(b * H_ + h) * 256 + dp;
    float den = 1e-6f, acc = 0.f;
#pragma unroll
    for (int e = 0; e < 16; ++e) {
        float q = sq[threadIdx.y][h * 16 + e];
        den = fmaf(q, ks[e], den);
        acc = fmaf(q, kvp[e * 16], acc);
    }
    out[(long long)row * D_ + o] = acc / den;
}

// ---------------- fused (residual|relu) + LayerNorm (in-place safe)
__global__ __launch_bounds__(256) void addln_kernel(
    const float* __restrict__ xin, const float* __restrict__ addend,
    const float* __restrict__ g, const float* __restrict__ beta,
    float* __restrict__ outp, int relu_mode)
{
    const int row = blockIdx.x * 4 + threadIdx.y;
    const int lane = threadIdx.x;
    const long long base = (long long)row * D_;
    float v0 = xin[base + lane], v1 = xin[base + lane + 64];
    if (addend) { v0 += addend[base + lane]; v1 += addend[base + lane + 64]; }
    if (relu_mode) { v0 = fmaxf(v0, 0.f); v1 = fmaxf(v1, 0.f); }
    float s = v0 + v1;
#pragma unroll
    for (int off = 32; off; off >>= 1) s += __shfl_xor(s, off);
    const float mean = s * (1.f / 128.f);
    const float c0 = v0 - mean, c1 = v1 - mean;
    float vs = c0 * c0 + c1 * c1;
#pragma unroll
    for (int off = 32; off; off >>= 1) vs += __shfl_xor(vs, off);
    const float rstd = rsqrtf(vs * (1.f / 128.f) + 1e-5f);
    outp[base + lane]      = c0 * rstd * g[lane] + beta[lane];
    outp[base + lane + 64] = c1 * rstd * g[lane + 64] + beta[lane + 64];
}

// ---------------- driver ----------------
extern "C" void kernel_launch(void* const* d_in, const int* in_sizes, int n_in,
                              void* d_out, int out_size, void* d_ws, size_t ws_size,
                              hipStream_t stream)
{
    (void)in_sizes; (void)n_in; (void)out_size; (void)ws_size;

    const float* x_in    = (const float*)d_in[0];
    const float* mem     = (const float*)d_in[1];
    const float* data    = (const float*)d_in[2];
    const float* support = (const float*)d_in[3];
    const float* Wq  = (const float*)d_in[4];
    const float* bq  = (const float*)d_in[5];
    const float* Wk  = (const float*)d_in[6];
    const float* bk  = (const float*)d_in[7];
    const float* Wv  = (const float*)d_in[8];
    const float* bv  = (const float*)d_in[9];
    const float* Wo  = (const float*)d_in[10];
    const float* bo  = (const float*)d_in[11];
    const float* W1  = (const float*)d_in[12];
    const float* b1  = (const float*)d_in[13];
    const float* W2  = (const float*)d_in[14];
    const float* b2  = (const float*)d_in[15];
    const float* W3  = (const float*)d_in[16];
    const float* b3  = (const float*)d_in[17];
    const float* lng = (const float*)d_in[18];
    const float* lnb = (const float*)d_in[19];
    const float* gcnW= (const float*)d_in[20];
    const float* gcnb= (const float*)d_in[21];
    const float* skW = (const float*)d_in[22];
    const float* skb = (const float*)d_in[23];
    const float* outg= (const float*)d_in[24];
    const float* outb= (const float*)d_in[25];

    float* ws = (float*)d_ws;
    // workspace map (floats): total ~23.15M floats = 92.6 MB
    float* X    = ws;                          // [B][7800][128]
    float* POOL = ws + 8000000LL;              // 11.6M floats transient
    bf16*  WBF  = (bf16*)(ws + 19600000LL);    // ~7.0M bf16
    float* BQKV = ws + 23100000LL;             // [6][384]
    float* SKB2 = ws + 23110000LL;             // [3][24][128]
    float* KVB  = ws + 23120000LL;             // [8][8][16][16]
    float* KSB  = ws + 23140000LL;             // [8][8][16]

    // WBF internal offsets (bf16 elements)
    bf16* WQKVT = WBF + 0;         // [6][384][128]  (Wq^T|Wk^T|Wv^T)
    bf16* WOT   = WBF + 294912;    // [6][128][128]
    bf16* W1T   = WBF + 393216;    // [3][512][128]
    bf16* W2T   = WBF + 589824;    // [3][128][512]
    bf16* W3T   = WBF + 786432;    // [3][325][128]
    bf16* SKWT  = WBF + 911232;    // [3][128][128]
    bf16* SUPT  = WBF + 960384;    // [325][384] (zero-padded K)
    bf16* GSKT  = WBF + 1085184;   // [3][24][128][640]  ((gcnW@skW)^T)

    float* SKIP = (float*)d_out;
    const int BIG = 1 << 30;
    dim3 blk(32, 8);
    auto TG = [](int ldd, int C, int z) { return dim3((ldd + 31) / 32, (C + 31) / 32, z); };

    // ================= prepass =================
    tconv<0><<<TG(128,128,6),blk,0,stream>>>(Wq, WQKVT,          128,128,128, 16384, 128, 49152);
    tconv<0><<<TG(128,128,6),blk,0,stream>>>(Wk, WQKVT + 16384,  128,128,128, 16384, 128, 49152);
    tconv<0><<<TG(128,128,6),blk,0,stream>>>(Wv, WQKVT + 32768,  128,128,128, 16384, 128, 49152);
    tconv<0><<<TG(128,128,6),blk,0,stream>>>(Wo, WOT,            128,128,128, 16384, 128, 16384);
    tconv<0><<<TG(128,512,3),blk,0,stream>>>(W1, W1T,            128,512,512, 65536, 128, 65536);
    tconv<0><<<TG(512,128,3),blk,0,stream>>>(W2, W2T,            512,128,128, 65536, 512, 65536);
    tconv<0><<<TG(128,325,3),blk,0,stream>>>(W3, W3T,            128,325,325, 41600, 128, 41600);
    tconv<0><<<TG(128,128,3),blk,0,stream>>>(skW, SKWT,          128,128,128, 16384, 128, 16384);
    tconv<0><<<TG(384,325,1),blk,0,stream>>>(support, SUPT,      325,325,325, 0,     384, 0);
    // gcnW -> bf16 (transient in POOL), then GSKT[i][l] = (skW^T) @ (gcnW[i][l])^T-as-Bt
    bf16* gcnWbf = (bf16*)POOL;   // [3][24][640][128]
    conv_k<<<4096,256,0,stream>>>(gcnW, gcnWbf, 5898240LL, 128, 128, 128);
    for (int i = 0; i < NL_; ++i)
        gemm1(stream, 1, SKWT + i*16384, gcnWbf + (long long)i*1966080, nullptr,
              GSKT + (long long)i*1966080,
              128, 640, 128, 0, 81920, 81920, 128, 128, 640, 24, BIG, 0, 0, EPI_NONE, 1);
    skb2_k<<<72,128,0,stream>>>(gcnb, skW, skb, SKB2);
    cbias_k<<<6,384,0,stream>>>(bq, bk, bv, BQKV);
    hipMemsetAsync(SKIP, 0, (size_t)SZ * sizeof(float), stream);

    // ================= layers =================
    for (int i = 0; i < NL_; ++i) {
        const float* xc = (i == 0) ? x_in : X;

        // ---- self attention: fused QKV, 2 chunks of 4 batches ----
        {
            const int wi = i * 2;
            for (int c = 0; c < 2; ++c) {
                const int b0 = c * 4;
                float* Q  = POOL;
                bf16* KB  = (bf16*)(POOL + 4000000LL);
                bf16* VB  = (bf16*)(POOL + 6000000LL);
                float* PART = POOL + 8000000LL;
                float* OB = POOL + 4000000LL;
                MOut mo{};
                mo.d[0] = Q;  mo.sC[0] = 0; mo.ldc_[0] = 128; mo.flg[0] = (EPI_ELU1 << 1) | 0;
                mo.d[1] = KB; mo.sC[1] = 0; mo.ldc_[1] = 128; mo.flg[1] = (EPI_ELU1 << 1) | 1;
                mo.d[2] = VB; mo.sC[2] = 0; mo.ldc_[2] = 128; mo.flg[2] = (EPI_NONE << 1) | 1;
                gemm3(stream, xc + (long long)b0 * U_, WQKVT + (long long)wi*49152,
                      BQKV + wi*384, mo, 4*T_SELF, 384, 128, 128, 128);
                kv_part_bf16<<<dim3(16,H_,4),256,0,stream>>>(KB, VB, PART, T_SELF, 16);
                kv_reduce2<<<dim3(H_,4),256,0,stream>>>(PART, KVB, KSB, b0, 16);
                attn_out_kernel<<<4*T_SELF/2, dim3(128,2),0,stream>>>(Q, KVB, KSB, Q, T_SELF, b0);
                gemm1(stream, 0, Q, WOT + (long long)wi*16384, bo + wi*128, OB,
                      4*T_SELF, 128, 128, 0,0,0, 128,128,128, 1,1,0, 0, EPI_NONE, 0);
                addln_kernel<<<4*T_SELF/4, dim3(64,4),0,stream>>>(
                    xc + (long long)b0*U_, OB, lng + (i*3)*128, lnb + (i*3)*128,
                    X + (long long)b0*U_, 0);
            }
        }

        // ---- cross attention: fused KV, 2 chunks of 4 batches ----
        {
            const int wi = i * 2 + 1;
            for (int c = 0; c < 2; ++c) {
                const int b0 = c * 4;
                bf16* KB2 = (bf16*)POOL;
                bf16* VB2 = (bf16*)(POOL + 4000000LL);
                float* PART = POOL + 8000000LL;
                MOut mo{};
                mo.d[0] = KB2; mo.sC[0] = 0; mo.ldc_[0] = 128; mo.flg[0] = (EPI_ELU1 << 1) | 1;
                mo.d[1] = VB2; mo.sC[1] = 0; mo.ldc_[1] = 128; mo.flg[1] = (EPI_NONE << 1) | 1;
                mo.d[2] = nullptr;
                gemm3(stream, mem + (long long)b0 * T_CROSS * D_,
                      WQKVT + (long long)wi*49152 + 16384, BQKV + wi*384 + 128, mo,
                      4*T_CROSS, 256, 128, 128, 128);
                kv_part_bf16<<<dim3(31,H_,4),256,0,stream>>>(KB2, VB2, PART, T_CROSS, 31);
                kv_reduce2<<<dim3(H_,4),256,0,stream>>>(PART, KVB, KSB, b0, 31);
                float* Q  = POOL;
                float* OB = POOL + 4000000LL;
                gemm1(stream, 0, X + (long long)b0*U_, WQKVT + (long long)wi*49152,
                      BQKV + wi*384, Q, 4*T_SELF, 128, 128, 0,0,0, 128,128,128, 1,1,0, 0, EPI_ELU1, 0);
                attn_out_kernel<<<4*T_SELF/2, dim3(128,2),0,stream>>>(Q, KVB, KSB, Q, T_SELF, b0);
                gemm1(stream, 0, Q, WOT + (long long)wi*16384, bo + wi*128, OB,
                      4*T_SELF, 128, 128, 0,0,0, 128,128,128, 1,1,0, 0, EPI_NONE, 0);
                addln_kernel<<<4*T_SELF/4, dim3(64,4),0,stream>>>(
                    X + (long long)b0*U_, OB, lng + (i*3+1)*128, lnb + (i*3+1)*128,
                    X + (long long)b0*U_, 0);
            }
        }

        // ---- FFN + adjacency + diffusion + fused GCN/skip: 4 chunks of 2 batches ----
        for (int c = 0; c < 4; ++c) {
            const int b0 = c * 2;
            float* Xb = X + (long long)b0 * U_;
            const float* datab = data + (long long)b0 * U_;

            bf16*  FFH  = (bf16*)POOL;                     // [15600][512]
            float* Y    = POOL + 4000000LL;                // [15600][128]
            bf16*  AS   = (bf16*)(POOL + 6000000LL);       // [15600][325]
            bf16*  AST  = (bf16*)(POOL + 8600000LL);       // [48][325][384]
            bf16*  Hb   = (bf16*)POOL;                     // [48][325][640]
            bf16*  DTB  = (bf16*)(POOL + 5000000LL);       // [48][128][384]
            bf16*  S1CT = (bf16*)(POOL + 6200000LL);       // [48][128][384]
            bf16*  A1CT = (bf16*)(POOL + 7400000LL);       // [48][128][384]

            gemm1(stream, 0, Xb, W1T + (long long)i*65536, b1 + i*512, FFH,
                  2*T_SELF, 512, 128, 0,0,0, 128,128,512, 1,1,0, 0, EPI_GELU, 1);
            gemm1(stream, 1, FFH, W2T + (long long)i*65536, b2 + i*128, Y,
                  2*T_SELF, 128, 512, 0,0,0, 512,512,128, 1,1,0, 0, EPI_NONE, 0);
            gemm1(stream, 0, Y, W3T + (long long)i*41600, b3 + i*325, AS,
                  2*T_SELF, 325, 128, 0,0,0, 128,128,325, 1,1,0, 0, EPI_NONE, 1);
            addln_kernel<<<2*T_SELF/4, dim3(64,4),0,stream>>>(
                Xb, Y, lng + (i*3+2)*128, lnb + (i*3+2)*128, Xb, 0);

            // As^T (per slice) and data^T, K-padded to 384
            tconv<1><<<TG(384,325,48),blk,0,stream>>>(AS, AST, 325,325,325, 105625, 384, 124800);
            tconv<0><<<TG(384,128,48),blk,0,stream>>>(datab, DTB, 325,128,128, 41600, 384, 49152);
            // H p0 = bf16(data), ldc 640
            conv_k<<<4096,256,0,stream>>>(datab, Hb, (long long)2*T_SELF*128, 128, 128, 640);
            // s1t -> H p1
            gemm1(stream, 1, SUPT, DTB, nullptr, Hb + 128,
                  325, 128, 384, 0, 49152, 208000, 384, 384, 640, 48, BIG, 0, 0, EPI_NONE, 1);
            tconv<1><<<TG(384,128,48),blk,0,stream>>>(Hb + 128, S1CT, 325,128,640, 208000, 384, 49152);
            // s2t -> H p2
            gemm1(stream, 1, SUPT, S1CT, nullptr, Hb + 256,
                  325, 128, 384, 0, 49152, 208000, 384, 384, 640, 48, BIG, 0, 0, EPI_NONE, 1);
            // a1t -> H p3
            gemm1(stream, 1, AST, DTB, nullptr, Hb + 384,
                  325, 128, 384, 124800, 49152, 208000, 384, 384, 640, 48, BIG, 0, 0, EPI_NONE, 1);
            tconv<1><<<TG(384,128,48),blk,0,stream>>>(Hb + 384, A1CT, 325,128,640, 208000, 384, 49152);
            // a2t -> H p4
            gemm1(stream, 1, AST, A1CT, nullptr, Hb + 512,
                  325, 128, 384, 124800, 49152, 208000, 384, 384, 640, 48, BIG, 0, 0, EPI_NONE, 1);
            // fused GCN + skip-conv, accumulate into SKIP
            gemm1(stream, 1, Hb, GSKT + (long long)i*1966080, SKB2 + i*3072,
                  SKIP + (long long)b0*U_,
                  325, 128, 640, 208000, 81920, 41600, 640, 640, 128, 48, 24, 128, 1, EPI_NONE, 0);
        }
    }

    addln_kernel<<<ROWS/4, dim3(64,4),0,stream>>>(SKIP, nullptr, outg, outb, SKIP, 1);
}

// Round 5
// 4221.699 us; speedup vs baseline: 4.7767x; 1.7347x over previous
//
#include <hip/hip_runtime.h>
#include <hip/hip_bf16.h>
#include <math.h>

// ---------------- problem constants ----------------
#define B_   8
#define L_   24
#define LP_  48
#define N_   325
#define D_   128
#define H_   8
#define NL_  3
#define DFF_ 512

typedef __attribute__((ext_vector_type(8))) short s16x8;
typedef __attribute__((ext_vector_type(4))) float f32x4;
typedef __hip_bfloat16 bf16;

static const int  ROWS    = B_ * L_ * N_;        // 62400
static const int  T_SELF  = L_ * N_;             // 7800
static const int  T_CROSS = LP_ * N_;            // 15600
static const long long U_ = (long long)T_SELF * D_;   // 998,400
static const long long SZ = (long long)B_ * U_;       // 7,987,200

enum { EPI_NONE = 0, EPI_ELU1 = 1, EPI_GELU = 2 };

struct MOut { void* d[3]; long long sC[3]; int ldc_[3]; int flg[3]; };  // flg = obf | (epi<<1)

__device__ __forceinline__ float apply_epi(float v, int epi) {
    if (epi == EPI_ELU1) return (v > 0.f) ? (v + 1.f) : expf(v);
    if (epi == EPI_GELU) return 0.5f * v * (1.f + erff(v * 0.70710678118654752f));
    return v;
}

// =====================================================================
// MFMA GEMM, 128x128 tile, 4 waves, BK=64. REQUIRES K % 64 == 0.
// C[z][M][Nc] (=/+=) epi( sum_k A[z][m][k] * Bt[z%bmod][n][k] + bias )
// bias: per-col bp[n], or per-row bp[m] if rowbias. MULTI: per-col-block outs.
// =====================================================================
template<int ABF, int MULTI>
__global__ __launch_bounds__(256) void gk(
    const void* __restrict__ Av, const bf16* __restrict__ Bt,
    const float* __restrict__ bias, void* __restrict__ Cv, MOut mo,
    int M, int Nc, int K,
    long long sA, long long sB, long long sC,
    int lda, int ldb, int ldc,
    int bmod, long long sBias, int accum, int epi, int obf, int rowbias)
{
    const int batch = blockIdx.z;
    const int m0 = blockIdx.y * 128, n0 = blockIdx.x * 128;
    const int tid = threadIdx.x, lane = tid & 63;
    const int w = tid >> 6, wm = w >> 1, wn = w & 1;
    const int r16 = lane & 15, kb = lane >> 4;

    __shared__ bf16 shA[128][72];   // pad 72 -> <=2-way bank alias (free)
    __shared__ bf16 shB[128][72];

    const float* Af = ABF ? nullptr : ((const float*)Av + (long long)batch * sA);
    const bf16*  Ab = ABF ? ((const bf16*)Av + (long long)batch * sA) : nullptr;
    const bf16*  Bp = Bt + (long long)(batch % bmod) * sB;

    f32x4 acc[4][4];
#pragma unroll
    for (int i = 0; i < 4; ++i)
#pragma unroll
        for (int j = 0; j < 4; ++j) acc[i][j] = f32x4{0.f, 0.f, 0.f, 0.f};

    for (int k0 = 0; k0 < K; k0 += 64) {
#pragma unroll
        for (int s = 0; s < 4; ++s) {
            int slot = tid + s * 256;
            int row = slot >> 3, kg = slot & 7;
            int m = m0 + row, k = k0 + kg * 8;
            union { s16x8 v; bf16 h[8]; } val;
            if (m < M) {
                if (ABF) {
                    val.v = *(const s16x8*)(Ab + (long long)m * lda + k);
                } else {
                    f32x4 v0 = *(const f32x4*)(Af + (long long)m * lda + k);
                    f32x4 v1 = *(const f32x4*)(Af + (long long)m * lda + k + 4);
#pragma unroll
                    for (int e = 0; e < 4; ++e) {
                        val.h[e]     = __float2bfloat16(v0[e]);
                        val.h[e + 4] = __float2bfloat16(v1[e]);
                    }
                }
            } else {
#pragma unroll
                for (int e = 0; e < 8; ++e) val.h[e] = __float2bfloat16(0.f);
            }
            *(s16x8*)&shA[row][kg * 8] = val.v;
        }
#pragma unroll
        for (int s = 0; s < 4; ++s) {
            int slot = tid + s * 256;
            int row = slot >> 3, kg = slot & 7;
            int n = n0 + row, k = k0 + kg * 8;
            union { s16x8 v; bf16 h[8]; } val;
            if (n < Nc) {
                val.v = *(const s16x8*)(Bp + (long long)n * ldb + k);
            } else {
#pragma unroll
                for (int e = 0; e < 8; ++e) val.h[e] = __float2bfloat16(0.f);
            }
            *(s16x8*)&shB[row][kg * 8] = val.v;
        }
        __syncthreads();
#pragma unroll
        for (int kh = 0; kh < 2; ++kh) {
            s16x8 av[4], bv[4];
#pragma unroll
            for (int mi = 0; mi < 4; ++mi)
                av[mi] = *(const s16x8*)&shA[wm * 64 + mi * 16 + r16][kh * 32 + kb * 8];
#pragma unroll
            for (int ni = 0; ni < 4; ++ni)
                bv[ni] = *(const s16x8*)&shB[wn * 64 + ni * 16 + r16][kh * 32 + kb * 8];
#pragma unroll
            for (int mi = 0; mi < 4; ++mi)
#pragma unroll
                for (int ni = 0; ni < 4; ++ni)
                    acc[mi][ni] = __builtin_amdgcn_mfma_f32_16x16x32_bf16(
                        av[mi], bv[ni], acc[mi][ni], 0, 0, 0);
        }
        __syncthreads();
    }

    int epi_ = epi, obf_ = obf, ldcc = ldc;
    long long scc = sC;
    void* dst = Cv;
    if (MULTI) {
        const int bx = blockIdx.x;
        epi_ = mo.flg[bx] >> 1; obf_ = mo.flg[bx] & 1;
        ldcc = mo.ldc_[bx]; scc = mo.sC[bx]; dst = mo.d[bx];
    }
    float* Cf = (float*)dst + (long long)batch * scc;
    bf16*  Cb = (bf16*)dst  + (long long)batch * scc;
    const float* bp = bias ? (bias + (long long)(batch % bmod) * sBias) : nullptr;
#pragma unroll
    for (int mi = 0; mi < 4; ++mi) {
#pragma unroll
        for (int ni = 0; ni < 4; ++ni) {
#pragma unroll
            for (int rr = 0; rr < 4; ++rr) {
                int m = m0 + wm * 64 + mi * 16 + kb * 4 + rr;
                int ln = wn * 64 + ni * 16 + r16;
                int n = n0 + ln;
                if (m >= M || n >= Nc) continue;
                float v = acc[mi][ni][rr];
                if (bp) v += rowbias ? bp[m] : bp[n];
                v = apply_epi(v, epi_);
                long long ci = (long long)m * ldcc + (MULTI ? ln : n);
                if (obf_) Cb[ci] = __float2bfloat16(v);
                else { if (accum) Cf[ci] += v; else Cf[ci] = v; }
            }
        }
    }
}

static inline void gemm1(hipStream_t st, int abf, const void* A, const bf16* Bt,
                         const float* bias, void* C,
                         int M, int Nc, int K,
                         long long sA, long long sB, long long sC,
                         int lda, int ldb, int ldc,
                         int z, int bmod, long long sBias, int accum, int epi, int obf,
                         int rowbias = 0)
{
    dim3 g((Nc + 127) / 128, (M + 127) / 128, z);
    MOut mo{};
    if (abf) gk<1,0><<<g,256,0,st>>>(A,Bt,bias,C,mo,M,Nc,K,sA,sB,sC,lda,ldb,ldc,bmod,sBias,accum,epi,obf,rowbias);
    else     gk<0,0><<<g,256,0,st>>>(A,Bt,bias,C,mo,M,Nc,K,sA,sB,sC,lda,ldb,ldc,bmod,sBias,accum,epi,obf,rowbias);
}

static inline void gemm3(hipStream_t st, int abf, const void* A, const bf16* Bt,
                         const float* bias, const MOut& mo, int M, int Nc, int K,
                         int lda, int ldb)
{
    dim3 g(Nc / 128, (M + 127) / 128, 1);
    if (abf) gk<1,1><<<g,256,0,st>>>(A,Bt,bias,nullptr,mo,M,Nc,K,0,0,0,lda,ldb,0,1,0,0,0,0,0);
    else     gk<0,1><<<g,256,0,st>>>(A,Bt,bias,nullptr,mo,M,Nc,K,0,0,0,lda,ldb,0,1,0,0,0,0,0);
}

// =====================================================================
// transpose-convert: dst[z][c][r] = src[z][r][c], bf16 out, zero r in [R,ldd)
// =====================================================================
template<int SBF>
__global__ __launch_bounds__(256) void tconv(
    const void* __restrict__ srcv, bf16* __restrict__ dst,
    int R, int C, int lds_, long long sS, int ldd, long long sD)
{
    const int bz = blockIdx.z;
    const float* sf = SBF ? nullptr : ((const float*)srcv + (long long)bz * sS);
    const bf16* sb = SBF ? ((const bf16*)srcv + (long long)bz * sS) : nullptr;
    bf16* dp = dst + (long long)bz * sD;
    __shared__ float t[32][33];
    const int r0 = blockIdx.x * 32, c0 = blockIdx.y * 32;
    for (int i = threadIdx.y; i < 32; i += 8) {
        int r = r0 + i, c = c0 + threadIdx.x;
        float v = 0.f;
        if (r < R && c < C)
            v = SBF ? __bfloat162float(sb[(long long)r * lds_ + c]) : sf[(long long)r * lds_ + c];
        t[i][threadIdx.x] = v;
    }
    __syncthreads();
    for (int i = threadIdx.y; i < 32; i += 8) {
        int c = c0 + i, r = r0 + threadIdx.x;
        if (c < C && r < ldd) dp[(long long)c * ldd + r] = __float2bfloat16(t[threadIdx.x][i]);
    }
}

// strided f32 -> bf16 convert
__global__ __launch_bounds__(256) void conv_k(
    const float* __restrict__ src, bf16* __restrict__ dst,
    long long total, int C, int slds, int dldd)
{
    for (long long idx = blockIdx.x * 256LL + threadIdx.x; idx < total;
         idx += (long long)gridDim.x * 256) {
        long long r = idx / C; int c = (int)(idx - r * C);
        dst[r * dldd + c] = __float2bfloat16(src[r * slds + c]);
    }
}

// GSUM[j] = sum_i GSKT[i][j]  (j over 24*128*640)
__global__ __launch_bounds__(256) void gsum_k(
    const bf16* __restrict__ gskt, bf16* __restrict__ gsum, long long per)
{
    for (long long j = blockIdx.x * 256LL + threadIdx.x; j < per;
         j += (long long)gridDim.x * 256) {
        float a = __bfloat162float(gskt[j]) + __bfloat162float(gskt[per + j])
                + __bfloat162float(gskt[2 * per + j]);
        gsum[j] = __float2bfloat16(a);
    }
}

// BSK[l][o] = sum_i ( skb[i][o] + sum_c gcnb[i*24+l][c] * skW[i][c][o] )
__global__ __launch_bounds__(128) void bsk_k(
    const float* __restrict__ gcnb, const float* __restrict__ skW,
    const float* __restrict__ skb, float* __restrict__ out)
{
    const int l = blockIdx.x, o = threadIdx.x;
    float acc = 0.f;
    for (int i = 0; i < NL_; ++i) {
        acc += skb[i * 128 + o];
        const float* gb = gcnb + (i * 24 + l) * 128;
        const float* sw = skW + i * 16384;
        for (int c = 0; c < 128; ++c) acc += gb[c] * sw[c * 128 + o];
    }
    out[l * 128 + o] = acc;
}

// bqkv[wi] = bq | bk | bv
__global__ __launch_bounds__(384) void cbias_k(
    const float* __restrict__ bq, const float* __restrict__ bk,
    const float* __restrict__ bv, float* __restrict__ bqkv)
{
    const int wi = blockIdx.x, j = threadIdx.x;
    float v = (j < 128) ? bq[wi * 128 + j] : (j < 256) ? bk[wi * 128 + j - 128] : bv[wi * 128 + j - 256];
    bqkv[wi * 384 + j] = v;
}

// ---------------- linear attention partial kv ----------------
__global__ __launch_bounds__(256) void kv_part_bf16(
    const bf16* __restrict__ kp, const bf16* __restrict__ vp,
    float* __restrict__ part, int T, int TC)
{
    const int z = blockIdx.z, h = blockIdx.y, tc = blockIdx.x;
    kp += (long long)z * T * D_;
    vp += (long long)z * T * D_;
    const int t0 = tc * 512;
    const int tend = min(T, t0 + 512);
    const int tid = threadIdx.x;
    const int e = tid >> 4, d = tid & 15;
    __shared__ float sk[64][16];
    __shared__ float sv[64][16];
    float acc = 0.f, asum = 0.f;
    for (int tb = t0; tb < tend; tb += 64) {
#pragma unroll
        for (int r = 0; r < 4; ++r) {
            int idx = tid + r * 256, tt = idx >> 4, c = idx & 15;
            int t = tb + tt;
            float kk = 0.f, vv = 0.f;
            if (t < tend) {
                long long gi = (long long)t * D_ + h * 16 + c;
                kk = __bfloat162float(kp[gi]);
                vv = __bfloat162float(vp[gi]);
            }
            sk[tt][c] = kk; sv[tt][c] = vv;
        }
        __syncthreads();
#pragma unroll 8
        for (int tt = 0; tt < 64; ++tt) {
            float ke = sk[tt][e];
            acc  = fmaf(ke, sv[tt][d], acc);
            asum += ke;
        }
        __syncthreads();
    }
    float* pp = part + (((long long)z * TC + tc) * H_ + h) * 272;
    pp[e * 16 + d] = acc;
    if (d == 0) pp[256 + e] = asum;
}

__global__ __launch_bounds__(256) void kv_reduce2(
    const float* __restrict__ part, float* __restrict__ kv,
    float* __restrict__ ksum, int b0, int TC)
{
    const int h = blockIdx.x, z = blockIdx.y, b = b0 + z;
    const float* pz = part + (long long)z * TC * H_ * 272;
    const int tid = threadIdx.x, e = tid >> 4, d = tid & 15;
    float acc = 0.f;
    for (int tc = 0; tc < TC; ++tc) acc += pz[((long long)tc * H_ + h) * 272 + e * 16 + d];
    kv[((long long)(b * H_ + h) * 16 + e) * 16 + d] = acc;
    if (d == 0) {
        float s = 0.f;
        for (int tc = 0; tc < TC; ++tc) s += pz[((long long)tc * H_ + h) * 272 + 256 + e];
        ksum[(b * H_ + h) * 16 + e] = s;
    }
}

// ---------------- attention combine, bf16 in/out, in-place safe ----------
__global__ __launch_bounds__(256) void attn_out_bf(
    const bf16* __restrict__ qp, const float* __restrict__ kv,
    const float* __restrict__ ksum, bf16* __restrict__ out)
{
    const int row = blockIdx.x * 2 + threadIdx.y;
    const int o = threadIdx.x;
    const int h = o >> 4, dp = o & 15;
    __shared__ float sq[2][D_];
    const int b = row / T_SELF;
    sq[threadIdx.y][o] = __bfloat162float(qp[(long long)row * D_ + o]);
    __syncthreads();
    const float* ks  = ksum + (b * H_ + h) * 16;
    const float* kvp = kv + (long long)(b * H_ + h) * 256 + dp;
    float den = 1e-6f, acc = 0.f;
#pragma unroll
    for (int e = 0; e < 16; ++e) {
        float q = sq[threadIdx.y][h * 16 + e];
        den = fmaf(q, ks[e], den);
        acc = fmaf(q, kvp[e * 16], acc);
    }
    out[(long long)row * D_ + o] = __float2bfloat16(acc / den);
}

// ---------------- fused (residual|relu) + LayerNorm ----------------
template<int XBF, int OBF>
__global__ __launch_bounds__(256) void addln_k(
    const void* __restrict__ xin, const bf16* __restrict__ addend,
    const float* __restrict__ g, const float* __restrict__ beta,
    void* __restrict__ outp, int relu_mode)
{
    const int row = blockIdx.x * 4 + threadIdx.y;
    const int lane = threadIdx.x;
    const long long base = (long long)row * D_;
    float v0, v1;
    if (XBF) {
        v0 = __bfloat162float(((const bf16*)xin)[base + lane]);
        v1 = __bfloat162float(((const bf16*)xin)[base + lane + 64]);
    } else {
        v0 = ((const float*)xin)[base + lane];
        v1 = ((const float*)xin)[base + lane + 64];
    }
    if (addend) {
        v0 += __bfloat162float(addend[base + lane]);
        v1 += __bfloat162float(addend[base + lane + 64]);
    }
    if (relu_mode) { v0 = fmaxf(v0, 0.f); v1 = fmaxf(v1, 0.f); }
    float s = v0 + v1;
#pragma unroll
    for (int off = 32; off; off >>= 1) s += __shfl_xor(s, off);
    const float mean = s * (1.f / 128.f);
    const float c0 = v0 - mean, c1 = v1 - mean;
    float vs = c0 * c0 + c1 * c1;
#pragma unroll
    for (int off = 32; off; off >>= 1) vs += __shfl_xor(vs, off);
    const float rstd = rsqrtf(vs * (1.f / 128.f) + 1e-5f);
    const float r0 = c0 * rstd * g[lane] + beta[lane];
    const float r1 = c1 * rstd * g[lane + 64] + beta[lane + 64];
    if (OBF) {
        ((bf16*)outp)[base + lane]      = __float2bfloat16(r0);
        ((bf16*)outp)[base + lane + 64] = __float2bfloat16(r1);
    } else {
        ((float*)outp)[base + lane]      = r0;
        ((float*)outp)[base + lane + 64] = r1;
    }
}

// ---------------- driver ----------------
extern "C" void kernel_launch(void* const* d_in, const int* in_sizes, int n_in,
                              void* d_out, int out_size, void* d_ws, size_t ws_size,
                              hipStream_t stream)
{
    (void)in_sizes; (void)n_in; (void)out_size; (void)ws_size;

    const float* x_in    = (const float*)d_in[0];
    const float* mem     = (const float*)d_in[1];
    const float* data    = (const float*)d_in[2];
    const float* support = (const float*)d_in[3];
    const float* Wq  = (const float*)d_in[4];
    const float* bq  = (const float*)d_in[5];
    const float* Wk  = (const float*)d_in[6];
    const float* bk  = (const float*)d_in[7];
    const float* Wv  = (const float*)d_in[8];
    const float* bv  = (const float*)d_in[9];
    const float* Wo  = (const float*)d_in[10];
    const float* bo  = (const float*)d_in[11];
    const float* W1  = (const float*)d_in[12];
    const float* b1  = (const float*)d_in[13];
    const float* W2  = (const float*)d_in[14];
    const float* b2  = (const float*)d_in[15];
    const float* W3  = (const float*)d_in[16];
    const float* b3  = (const float*)d_in[17];
    const float* lng = (const float*)d_in[18];
    const float* lnb = (const float*)d_in[19];
    const float* gcnW= (const float*)d_in[20];
    const float* gcnb= (const float*)d_in[21];
    const float* skW = (const float*)d_in[22];
    const float* skb = (const float*)d_in[23];
    const float* outg= (const float*)d_in[24];
    const float* outb= (const float*)d_in[25];

    float* ws = (float*)d_ws;
    // ---- layout (floats): total ~23.3M fl = 93.2 MB ----
    bf16*  Xb16 = (bf16*)ws;                    // [8][7800][128] bf16 (8M slots)
    float* POOL = ws + 4000000LL;               // 14.8M floats transient
    bf16*  WBF  = (bf16*)(ws + 18800000LL);     // weights, bf16
    float* BQKV = ws + 23275008LL;              // [6][384]
    float* BSK  = ws + 23277504LL;              // [24][128]
    float* KVB  = ws + 23280576LL;              // [8][8][16][16]
    float* KSB  = ws + 23296960LL;              // [8][8][16]

    bf16* WQKVT = WBF + 0;          // [6][384][128]
    bf16* WOT   = WBF + 294912;     // [6][128][128]
    bf16* W1T   = WBF + 393216;     // [3][512][128]
    bf16* W2T   = WBF + 589824;     // [3][128][512]
    bf16* W3T   = WBF + 786432;     // [3][325][128]
    bf16* SKWT  = WBF + 911232;     // [3][128][128]
    bf16* SUPT  = WBF + 960384;     // [325][384]
    bf16* GSKT  = WBF + 1085184;    // [3][24][128][640]
    bf16* GSUM  = WBF + 6983424;    // [24][128][640]

    float* SKIP = (float*)d_out;
    const int BIG = 1 << 30;
    dim3 blk(32, 8);
    auto TG = [](int ldd, int C, int z) { return dim3((ldd + 31) / 32, (C + 31) / 32, z); };

    // ---------------- prepass: weights ----------------
    tconv<0><<<TG(128,128,6),blk,0,stream>>>(Wq, WQKVT,          128,128,128, 16384, 128, 49152);
    tconv<0><<<TG(128,128,6),blk,0,stream>>>(Wk, WQKVT + 16384,  128,128,128, 16384, 128, 49152);
    tconv<0><<<TG(128,128,6),blk,0,stream>>>(Wv, WQKVT + 32768,  128,128,128, 16384, 128, 49152);
    tconv<0><<<TG(128,128,6),blk,0,stream>>>(Wo, WOT,            128,128,128, 16384, 128, 16384);
    tconv<0><<<TG(128,512,3),blk,0,stream>>>(W1, W1T,            128,512,512, 65536, 128, 65536);
    tconv<0><<<TG(512,128,3),blk,0,stream>>>(W2, W2T,            512,128,128, 65536, 512, 65536);
    tconv<0><<<TG(128,325,3),blk,0,stream>>>(W3, W3T,            128,325,325, 41600, 128, 41600);
    tconv<0><<<TG(128,128,3),blk,0,stream>>>(skW, SKWT,          128,128,128, 16384, 128, 16384);
    tconv<0><<<TG(384,325,1),blk,0,stream>>>(support, SUPT,      325,325,325, 0,     384, 0);
    bf16* gcnWbf = (bf16*)POOL;   // [3*24*640][128] transient
    conv_k<<<4096,256,0,stream>>>(gcnW, gcnWbf, 5898240LL, 128, 128, 128);
    for (int i = 0; i < NL_; ++i)
        gemm1(stream, 1, SKWT + i*16384, gcnWbf + (long long)i*1966080, nullptr,
              GSKT + (long long)i*1966080,
              128, 640, 128, 0, 81920, 81920, 128, 128, 640, 24, BIG, 0, 0, EPI_NONE, 1);
    gsum_k<<<2048,256,0,stream>>>(GSKT, GSUM, 1966080LL);
    bsk_k<<<24,128,0,stream>>>(gcnb, skW, skb, BSK);
    cbias_k<<<6,384,0,stream>>>(bq, bk, bv, BQKV);
    hipMemsetAsync(SKIP, 0, (size_t)SZ * sizeof(float), stream);

    // ---------------- prepass: static diffusion channels + static skip ----------------
    // pool offsets (floats)
    for (int c = 0; c < 2; ++c) {                       // 4 batches, 96 (b,l) slices each
        const int b0 = c * 4;
        const float* datab = data + (long long)b0 * U_;
        bf16* data_bf = (bf16*)POOL;                    // [96*325][128]   @0 (2.0M fl)
        bf16* s1_mc   = (bf16*)(POOL + 2000000LL);      // [96][325][128]
        bf16* s2_mc   = (bf16*)(POOL + 4000000LL);      // [96][325][128]
        bf16* s1_cm   = (bf16*)(POOL + 6000000LL);      // [96][128][384] (pad-zero)
        bf16* DTB     = (bf16*)(POOL + 10000000LL);     // [96][128][384]
        hipMemsetAsync(s1_cm, 0, 4718592LL * 2, stream);
        conv_k<<<2048,256,0,stream>>>(datab, data_bf, 96LL*41600, 128, 128, 128);
        tconv<0><<<TG(384,128,96),blk,0,stream>>>(datab, DTB, 325,128,128, 41600, 384, 49152);
        // s1_mc[m][c] = sum_n sup[n][m] data[n][c]
        gemm1(stream, 1, SUPT, DTB, nullptr, s1_mc, 325,128,384,
              0, 49152, 41600, 384,384,128, 96, BIG, 0, 0, EPI_NONE, 1);
        // s1_cm[c][m]
        gemm1(stream, 1, DTB, SUPT, nullptr, s1_cm, 128,325,384,
              49152, 0, 49152, 384,384,384, 96, 1, 0, 0, EPI_NONE, 1);
        // s2_mc[m][c] = sum_n sup[n][m] s1[c][n]
        gemm1(stream, 1, SUPT, s1_cm, nullptr, s2_mc, 325,128,384,
              0, 49152, 41600, 384,384,128, 96, BIG, 0, 0, EPI_NONE, 1);
        // static skip += p0,p1,p2 (bias BSK on p0)
        gemm1(stream, 1, data_bf, GSUM + 0, BSK, SKIP + (long long)b0*U_,
              325,128,128, 41600, 81920, 41600, 128, 640, 128, 96, 24, 128, 1, EPI_NONE, 0);
        gemm1(stream, 1, s1_mc, GSUM + 128, nullptr, SKIP + (long long)b0*U_,
              325,128,128, 41600, 81920, 41600, 128, 640, 128, 96, 24, 0, 1, EPI_NONE, 0);
        gemm1(stream, 1, s2_mc, GSUM + 256, nullptr, SKIP + (long long)b0*U_,
              325,128,128, 41600, 81920, 41600, 128, 640, 128, 96, 24, 0, 1, EPI_NONE, 0);
    }

    // ---------------- layers ----------------
    for (int i = 0; i < NL_; ++i) {
        // ======== self attention (full batch) ========
        {
            const int wi = i * 2;
            bf16* Q  = (bf16*)POOL;                      // @0      (4M fl)
            bf16* KB = (bf16*)(POOL + 4000000LL);
            bf16* VB = (bf16*)(POOL + 8000000LL);
            float* PART = POOL + 12000000LL;             // 8*16*8*272
            bf16* OB = (bf16*)(POOL + 4000000LL);        // over KB (dead)
            MOut mo{};
            mo.d[0] = Q;  mo.sC[0] = 0; mo.ldc_[0] = 128; mo.flg[0] = (EPI_ELU1 << 1) | 1;
            mo.d[1] = KB; mo.sC[1] = 0; mo.ldc_[1] = 128; mo.flg[1] = (EPI_ELU1 << 1) | 1;
            mo.d[2] = VB; mo.sC[2] = 0; mo.ldc_[2] = 128; mo.flg[2] = (EPI_NONE << 1) | 1;
            if (i == 0) gemm3(stream, 0, x_in, WQKVT + (long long)wi*49152, BQKV + wi*384, mo, ROWS, 384, 128, 128, 128);
            else        gemm3(stream, 1, Xb16, WQKVT + (long long)wi*49152, BQKV + wi*384, mo, ROWS, 384, 128, 128, 128);
            kv_part_bf16<<<dim3(16,H_,8),256,0,stream>>>(KB, VB, PART, T_SELF, 16);
            kv_reduce2<<<dim3(H_,8),256,0,stream>>>(PART, KVB, KSB, 0, 16);
            attn_out_bf<<<ROWS/2, dim3(128,2),0,stream>>>(Q, KVB, KSB, Q);
            gemm1(stream, 1, Q, WOT + (long long)wi*16384, bo + wi*128, OB,
                  ROWS, 128, 128, 0,0,0, 128,128,128, 1,1,0, 0, EPI_NONE, 1);
            if (i == 0) addln_k<0,1><<<ROWS/4, dim3(64,4),0,stream>>>(
                x_in, OB, lng + (i*3)*128, lnb + (i*3)*128, Xb16, 0);
            else        addln_k<1,1><<<ROWS/4, dim3(64,4),0,stream>>>(
                Xb16, OB, lng + (i*3)*128, lnb + (i*3)*128, Xb16, 0);
        }

        // ======== cross attention (KV in 2 chunks, rest full batch) ========
        {
            const int wi = i * 2 + 1;
            for (int c = 0; c < 2; ++c) {
                const int b0 = c * 4;
                bf16* KB = (bf16*)POOL;                  // 4*15600*128 bf16
                bf16* VB = (bf16*)(POOL + 4000000LL);
                float* PART = POOL + 8000000LL;          // 4*31*8*272
                MOut mo{};
                mo.d[0] = KB; mo.sC[0] = 0; mo.ldc_[0] = 128; mo.flg[0] = (EPI_ELU1 << 1) | 1;
                mo.d[1] = VB; mo.sC[1] = 0; mo.ldc_[1] = 128; mo.flg[1] = (EPI_NONE << 1) | 1;
                mo.d[2] = nullptr;
                gemm3(stream, 0, mem + (long long)b0 * T_CROSS * D_,
                      WQKVT + (long long)wi*49152 + 16384, BQKV + wi*384 + 128, mo,
                      4*T_CROSS, 256, 128, 128, 128);
                kv_part_bf16<<<dim3(31,H_,4),256,0,stream>>>(KB, VB, PART, T_CROSS, 31);
                kv_reduce2<<<dim3(H_,4),256,0,stream>>>(PART, KVB, KSB, b0, 31);
            }
            bf16* Q  = (bf16*)POOL;
            bf16* OB = (bf16*)(POOL + 4000000LL);
            gemm1(stream, 1, Xb16, WQKVT + (long long)wi*49152, BQKV + wi*384, Q,
                  ROWS, 128, 128, 0,0,0, 128,128,128, 1,1,0, 0, EPI_ELU1, 1);
            attn_out_bf<<<ROWS/2, dim3(128,2),0,stream>>>(Q, KVB, KSB, Q);
            gemm1(stream, 1, Q, WOT + (long long)wi*16384, bo + wi*128, OB,
                  ROWS, 128, 128, 0,0,0, 128,128,128, 1,1,0, 0, EPI_NONE, 1);
            addln_k<1,1><<<ROWS/4, dim3(64,4),0,stream>>>(
                Xb16, OB, lng + (i*3+1)*128, lnb + (i*3+1)*128, Xb16, 0);
        }

        // ======== FFN + adjacency + diffusion + dynamic skip (2 chunks of 4 batches) ========
        for (int c = 0; c < 2; ++c) {
            const int b0 = c * 4;
            bf16* Xb = Xb16 + (long long)b0 * U_;

            bf16* FFH   = (bf16*)POOL;                    // [31200][512]      @0..8M
            bf16* Ybf   = (bf16*)(POOL + 8000000LL);      // [31200][128]      @8..10M
            bf16* AST   = (bf16*)POOL;                    // [96][325][384]    @0..6M (pad-zero)
            bf16* a1_cm = (bf16*)(POOL + 6000000LL);      // [96][128][384]    (pad-zero)
            bf16* DTB   = (bf16*)(POOL + 10000000LL);     // [96][128][384]
            bf16* a1_mc = (bf16*)(POOL + 12400000LL);     // [96][325][128]

            gemm1(stream, 1, Xb, W1T + (long long)i*65536, b1 + i*512, FFH,
                  4*T_SELF, 512, 128, 0,0,0, 128,128,512, 1,1,0, 0, EPI_GELU, 1);
            gemm1(stream, 1, FFH, W2T + (long long)i*65536, b2 + i*128, Ybf,
                  4*T_SELF, 128, 512, 0,0,0, 512,512,128, 1,1,0, 0, EPI_NONE, 1);
            addln_k<1,1><<<4*T_SELF/4, dim3(64,4),0,stream>>>(
                Xb, Ybf, lng + (i*3+2)*128, lnb + (i*3+2)*128, Xb, 0);
            // AST[slice][m][n] = sum_d W3T[m][d]*Y[slice][n][d] + b3[m]   (As^T directly)
            hipMemsetAsync(AST, 0, 11980800LL * 2, stream);
            gemm1(stream, 1, W3T + (long long)i*41600, Ybf, b3 + i*325, AST,
                  325, 325, 128, 0, 41600, 124800, 128, 128, 384, 96, BIG, 0, 0, EPI_NONE, 1, /*rowbias*/1);
            tconv<0><<<TG(384,128,96),blk,0,stream>>>(data + (long long)b0*U_, DTB,
                  325,128,128, 41600, 384, 49152);
            hipMemsetAsync(a1_cm, 0, 4718592LL * 2, stream);
            // a1_mc[m][c] = sum_n AST[m][n]*DTB[c][n]
            gemm1(stream, 1, AST, DTB, nullptr, a1_mc, 325,128,384,
                  124800, 49152, 41600, 384,384,128, 96, BIG, 0, 0, EPI_NONE, 1);
            // a1_cm[c][m] = sum_n DTB[c][n]*AST[m][n]
            gemm1(stream, 1, DTB, AST, nullptr, a1_cm, 128,325,384,
                  49152, 124800, 49152, 384,384,384, 96, BIG, 0, 0, EPI_NONE, 1);
            // skip += a1 @ G_{i,3}
            gemm1(stream, 1, a1_mc, GSKT + (long long)i*1966080 + 384, nullptr,
                  SKIP + (long long)b0*U_, 325,128,128,
                  41600, 81920, 41600, 128, 640, 128, 96, 24, 0, 1, EPI_NONE, 0);
            // a2_mc[m][c] = sum_n AST[m][n]*a1_cm[c][n]   (overwrites a1_mc)
            gemm1(stream, 1, AST, a1_cm, nullptr, a1_mc, 325,128,384,
                  124800, 49152, 41600, 384,384,128, 96, BIG, 0, 0, EPI_NONE, 1);
            // skip += a2 @ G_{i,4}
            gemm1(stream, 1, a1_mc, GSKT + (long long)i*1966080 + 512, nullptr,
                  SKIP + (long long)b0*U_, 325,128,128,
                  41600, 81920, 41600, 128, 640, 128, 96, 24, 0, 1, EPI_NONE, 0);
        }
    }

    // out = LN(relu(skip)) in place
    addln_k<0,0><<<ROWS/4, dim3(64,4),0,stream>>>(SKIP, nullptr, outg, outb, SKIP, 1);
}